// Round 8
// baseline (509.469 us; speedup 1.0000x reference)
//
#include <hip/hip_runtime.h>
#include <hip/hip_bf16.h>
#include <hip/hip_fp16.h>
#include <type_traits>

// combined bucket space: um buckets width 128 -> 157; mu buckets width 512 -> 196
#define NB_UM 157
#define NB_MU 196
#define NBALL 353
#define NBLK 256

#if defined(__has_builtin)
#if __has_builtin(__builtin_amdgcn_fdot2)
#define HAS_FDOT2 1
#endif
#endif

typedef _Float16 hv2 __attribute__((ext_vector_type(2)));

__device__ __forceinline__ float dot2f(unsigned a, unsigned b, float c) {
#ifdef HAS_FDOT2
    union U { unsigned u; hv2 h; };
    U ua, ub;
    ua.u = a; ub.u = b;
    return __builtin_amdgcn_fdot2(ua.h, ub.h, c, false);
#else
    __half2 ha = *(__half2*)&a, hb = *(__half2*)&b;
    float2 fa = __half22float2(ha), fb = __half22float2(hb);
    return c + fa.x * fb.x + fa.y * fb.y;
#endif
}

// ---------------- cast fp32 -> fp16 tables ----------------

__global__ __launch_bounds__(256) void cast_half2(const float* __restrict__ a,
                                                  __half* __restrict__ ah, int na,
                                                  const float* __restrict__ b,
                                                  __half* __restrict__ bh, int nb) {
    int i = blockIdx.x * blockDim.x + threadIdx.x;
    int st = gridDim.x * blockDim.x;
    for (int k = i; k < na / 2; k += st) {
        float2 v = ((const float2*)a)[k];
        ((__half2*)ah)[k] = __floats2half2_rn(v.x, v.y);
    }
    for (int k = i; k < nb / 2; k += st) {
        float2 v = ((const float2*)b)[k];
        ((__half2*)bh)[k] = __floats2half2_rn(v.x, v.y);
    }
}

// ---------------- pass 1: per-(bucket,block) histogram ----------------

__global__ __launch_bounds__(1024) void hist_part(const int* __restrict__ dst_um,
                                                  const int* __restrict__ dst_mu,
                                                  int* __restrict__ histM, int E) {
    __shared__ int h[NBALL];
    for (int i = threadIdx.x; i < NBALL; i += 1024) h[i] = 0;
    __syncthreads();
    int blk = blockIdx.x;
    int chunk = (E + NBLK - 1) / NBLK;
    int s = blk * chunk, e = min(E, s + chunk);
    for (int i = s + threadIdx.x; i < e; i += 1024) {
        atomicAdd(&h[dst_um[i] >> 7], 1);
        atomicAdd(&h[NB_UM + (dst_mu[i] >> 9)], 1);
    }
    __syncthreads();
    for (int i = threadIdx.x; i < NBALL; i += 1024) histM[i * NBLK + blk] = h[i];
}

// ---------------- pass 2: per-bucket wave scan over blocks ----------------

__global__ __launch_bounds__(256) void bucket_totals(int* __restrict__ histM,
                                                     int* __restrict__ btot, int nball) {
    int w = (blockIdx.x * blockDim.x + threadIdx.x) >> 6;
    int lane = threadIdx.x & 63;
    if (w >= nball) return;
    int* row = histM + w * NBLK;
    int v[4];
    int s = 0;
#pragma unroll
    for (int i = 0; i < 4; i++) {
        int c = row[lane * 4 + i];
        v[i] = s;
        s += c;
    }
    int incl = s;
    for (int d = 1; d < 64; d <<= 1) {
        int y = __shfl_up(incl, d, 64);
        if (lane >= d) incl += y;
    }
    int excl = incl - s;
#pragma unroll
    for (int i = 0; i < 4; i++) row[lane * 4 + i] = excl + v[i];
    if (lane == 63) btot[w] = incl;
}

// ---------------- pass 3: scan bucket totals ----------------

__global__ __launch_bounds__(256) void boff_scan(const int* __restrict__ btot,
                                                 int* __restrict__ boff, int nball,
                                                 int* __restrict__ off_um, int NM,
                                                 int* __restrict__ off_mu, int NU, int E) {
    __shared__ int sdata[256];
    int t = threadIdx.x;
    int v[8];
    int sum = 0;
#pragma unroll
    for (int i = 0; i < 8; i++) {
        int idx = t * 8 + i;
        int c = (idx < nball) ? btot[idx] : 0;
        v[i] = sum;
        sum += c;
    }
    sdata[t] = sum;
    __syncthreads();
    for (int s = 1; s < 256; s <<= 1) {
        int y = (t >= s) ? sdata[t - s] : 0;
        __syncthreads();
        sdata[t] += y;
        __syncthreads();
    }
    int base = (t == 0) ? 0 : sdata[t - 1];
#pragma unroll
    for (int i = 0; i < 8; i++) {
        int idx = t * 8 + i;
        if (idx < nball) boff[idx] = base + v[i];
    }
    if (t == 0) {
        boff[nball] = 2 * E;
        off_um[NM] = E;
        off_mu[NU] = E;
    }
}

// ---------------- pass 4: finalize off_mat ----------------

__global__ __launch_bounds__(256) void add_boff(int* __restrict__ histM,
                                                const int* __restrict__ boff, int n) {
    int st = gridDim.x * blockDim.x;
    for (int i = blockIdx.x * blockDim.x + threadIdx.x; i < n; i += st)
        histM[i] += boff[i >> 8];  // NBLK==256
}

// ---------------- pass 5: partition (block-private cursors in LDS) ----------------

__global__ __launch_bounds__(1024) void partition2(const int* __restrict__ src_um,
                                                   const int* __restrict__ dst_um,
                                                   const int* __restrict__ src_mu,
                                                   const int* __restrict__ dst_mu,
                                                   const int* __restrict__ histM,
                                                   int* __restrict__ tmp, int E) {
    __shared__ int cur[NBALL];
    int blk = blockIdx.x;
    for (int i = threadIdx.x; i < NBALL; i += 1024) cur[i] = histM[i * NBLK + blk];
    __syncthreads();
    int chunk = (E + NBLK - 1) / NBLK;
    int s = blk * chunk, e = min(E, s + chunk);
    for (int i = s + threadIdx.x; i < e; i += 1024) {
        int d = dst_um[i];
        int p = atomicAdd(&cur[d >> 7], 1);
        tmp[p] = src_um[i] | ((d & 127) << 20);
        int d2 = dst_mu[i];
        int q = atomicAdd(&cur[NB_UM + (d2 >> 9)], 1);
        tmp[q] = src_mu[i] | ((d2 & 511) << 20);
    }
}

// ---------------- pass 6: per-bucket CSR scatter ----------------

template <int W>
__global__ __launch_bounds__(256) void scatter_csr(const int* __restrict__ tmp,
                                                   const int* __restrict__ boff,
                                                   int* __restrict__ off,
                                                   int* __restrict__ csr, int n, int sub) {
    constexpr int EPT = (W + 255) / 256;  // elems per thread for the scan
    __shared__ int lcnt[W];
    __shared__ int lcur[W];
    __shared__ int sdata[256];
    int b = blockIdx.x;
    int t = threadIdx.x;
    int s = boff[b], e = boff[b + 1];
    for (int j = t; j < W; j += 256) lcnt[j] = 0;
    __syncthreads();
    for (int i = s + t; i < e; i += 256) atomicAdd(&lcnt[tmp[i] >> 20], 1);
    __syncthreads();
    // parallel exclusive scan of lcnt -> lcur (+s)
    int v[EPT];
    int sum = 0;
#pragma unroll
    for (int i = 0; i < EPT; i++) {
        int idx = t * EPT + i;
        int c = (idx < W) ? lcnt[idx] : 0;
        v[i] = sum;
        sum += c;
    }
    sdata[t] = sum;
    __syncthreads();
    for (int d = 1; d < 256; d <<= 1) {
        int y = (t >= d) ? sdata[t - d] : 0;
        __syncthreads();
        sdata[t] += y;
        __syncthreads();
    }
    int base = (t == 0) ? 0 : sdata[t - 1];
#pragma unroll
    for (int i = 0; i < EPT; i++) {
        int idx = t * EPT + i;
        if (idx < W) lcur[idx] = s + base + v[i];
    }
    __syncthreads();
    int rowbase = b * W;
    for (int j = t; j < W; j += 256)
        if (rowbase + j < n) off[rowbase + j] = lcur[j] - sub;
    __syncthreads();
    for (int i = s + t; i < e; i += 256) {
        int vv = tmp[i];
        int p = atomicAdd(&lcur[vv >> 20], 1);
        csr[p - sub] = vv & 0xFFFFF;
    }
}

// ---------------- segment mean (fp16 gather, one wave per dst row) ----------------

__device__ __forceinline__ void acc8(float* a, uint4 r) {
    const __half2* h = reinterpret_cast<const __half2*>(&r);
#pragma unroll
    for (int j = 0; j < 4; j++) {
        float2 f = __half22float2(h[j]);
        a[2 * j] += f.x;
        a[2 * j + 1] += f.y;
    }
}

template <int D>
__global__ __launch_bounds__(256) void agg_mean_h(const int* __restrict__ csr,
                                                  const int* __restrict__ off,
                                                  const __half* __restrict__ xh,
                                                  float* __restrict__ out, int nrows) {
    constexpr int LPE = D / 8;
    constexpr int GRP = 64 / LPE;
    int wave = (blockIdx.x * blockDim.x + threadIdx.x) >> 6;
    int lane = threadIdx.x & 63;
    int nwaves = (gridDim.x * blockDim.x) >> 6;
    int g = lane / LPE;
    int cl = lane % LPE;  // 8-col group
    for (int row = wave; row < nrows; row += nwaves) {
        int s = off[row], e = off[row + 1];
        float a[8] = {0.f, 0.f, 0.f, 0.f, 0.f, 0.f, 0.f, 0.f};
        for (int k = s + g; k < e; k += 2 * GRP) {
            int idx0 = csr[k];
            int k1 = k + GRP;
            int idx1 = (k1 < e) ? csr[k1] : -1;
            uint4 r0 = *(const uint4*)&xh[(long)idx0 * D + cl * 8];
            if (idx1 >= 0) {
                uint4 r1 = *(const uint4*)&xh[(long)idx1 * D + cl * 8];
                acc8(a, r0);
                acc8(a, r1);
            } else {
                acc8(a, r0);
            }
        }
        for (int m = LPE; m < 64; m <<= 1) {
#pragma unroll
            for (int j = 0; j < 8; j++) a[j] += __shfl_xor(a[j], m, 64);
        }
        if (g == 0) {
            float inv = 1.0f / fmaxf((float)(e - s), 1.0f);
            float4 r0 = make_float4(a[0] * inv, a[1] * inv, a[2] * inv, a[3] * inv);
            float4 r1 = make_float4(a[4] * inv, a[5] * inv, a[6] * inv, a[7] * inv);
            *(float4*)&out[(long)row * D + cl * 8] = r0;
            *(float4*)&out[(long)row * D + cl * 8 + 4] = r1;
        }
    }
}

// ---------------- dense: out = act([mean|xd] @ [Wl;Wr] + b) ----------------
// fp16 LDS staging for A and W^T, fp32 accumulate via v_dot2_f32_f16.
// sA: [64][K+8] halves (16B-aligned rows, 2-way conflicts only).
// sWt: [64][128] halves, 16B-chunk XOR swizzle (chunk ^= col&7) -> conflict-free.

template <int Dm, int Dd, bool RELU, typename TX, typename TO>
__global__ __launch_bounds__(256) void dense_gemm(const float* __restrict__ mean,
                                                  const TX* __restrict__ xd,
                                                  const float* __restrict__ Wl,
                                                  const float* __restrict__ Wr,
                                                  const float* __restrict__ bias,
                                                  TO* __restrict__ out, int n) {
    constexpr int K = Dm + Dd;           // 96 or 128 (multiple of 8)
    constexpr int SAP = K + 8;           // sA row stride in halves (16B multiple)
    __shared__ __align__(16) __half sA[64 * SAP];
    __shared__ __align__(16) __half sWt[64 * 128];
    __shared__ float sb[64];
    int t = threadIdx.x;
    int R0 = blockIdx.x * 64;

    // stage W transposed + swizzled
    for (int i = t; i < K * 16; i += 256) {
        int k = i >> 4, c = (i & 15) * 4;
        float4 v = (k < Dm) ? *(const float4*)&Wl[k * 64 + c]
                            : *(const float4*)&Wr[(k - Dm) * 64 + c];
        float vv[4] = {v.x, v.y, v.z, v.w};
#pragma unroll
        for (int jj = 0; jj < 4; jj++) {
            int col = c + jj;
            int phys = ((((k >> 3) ^ (col & 7)) << 3) | (k & 7));
            sWt[col * 128 + phys] = __float2half(vv[jj]);
        }
    }
    if (t < 64) sb[t] = bias[t];
    // stage A tile (fp16): row r cols [0,Dm) from mean, [Dm,K) from xd
    constexpr int QR = K / 4;
    for (int i = t; i < 64 * QR; i += 256) {
        int r = i / QR, c = (i % QR) * 4;
        int gr = R0 + r;
        float4 v = make_float4(0.f, 0.f, 0.f, 0.f);
        if (gr < n) {
            if (c < Dm) {
                v = *(const float4*)&mean[(long)gr * Dm + c];
            } else {
                if constexpr (std::is_same<TX, __half>::value) {
                    const __half* p = &xd[(long)gr * Dd + (c - Dm)];
                    v = make_float4(__half2float(p[0]), __half2float(p[1]),
                                    __half2float(p[2]), __half2float(p[3]));
                } else {
                    v = *(const float4*)&xd[(long)gr * Dd + (c - Dm)];
                }
            }
        }
        *(__half2*)&sA[r * SAP + c] = __floats2half2_rn(v.x, v.y);
        *(__half2*)&sA[r * SAP + c + 2] = __floats2half2_rn(v.z, v.w);
    }
    __syncthreads();

    int tx = t & 15, ty = t >> 4;
    int c0 = tx * 4, r0 = ty * 4;
    float acc[4][4];
    float4 bb = *(float4*)&sb[c0];
#pragma unroll
    for (int i = 0; i < 4; i++) {
        acc[i][0] = bb.x; acc[i][1] = bb.y; acc[i][2] = bb.z; acc[i][3] = bb.w;
    }
#pragma unroll
    for (int ch = 0; ch < K / 8; ++ch) {
        uint4 av[4], bv[4];
#pragma unroll
        for (int i = 0; i < 4; i++) av[i] = *(const uint4*)&sA[(r0 + i) * SAP + ch * 8];
#pragma unroll
        for (int j = 0; j < 4; j++) {
            int col = c0 + j;
            bv[j] = *(const uint4*)&sWt[col * 128 + ((ch ^ (col & 7)) << 3)];
        }
#pragma unroll
        for (int i = 0; i < 4; i++) {
            const unsigned* ap = (const unsigned*)&av[i];
#pragma unroll
            for (int j = 0; j < 4; j++) {
                const unsigned* bp = (const unsigned*)&bv[j];
                float a0 = dot2f(ap[0], bp[0], acc[i][j]);
                float a1 = dot2f(ap[1], bp[1], a0);
                float a2 = dot2f(ap[2], bp[2], a1);
                acc[i][j] = dot2f(ap[3], bp[3], a2);
            }
        }
    }
#pragma unroll
    for (int i = 0; i < 4; i++) {
        int gr = R0 + r0 + i;
        if (gr >= n) continue;
        float4 r;
        if (RELU) {
            r = make_float4(fmaxf(acc[i][0], 0.f), fmaxf(acc[i][1], 0.f),
                            fmaxf(acc[i][2], 0.f), fmaxf(acc[i][3], 0.f));
        } else {
            r = make_float4(acc[i][0], acc[i][1], acc[i][2], acc[i][3]);
        }
        if constexpr (std::is_same<TO, __half>::value) {
            __half2 h01 = __floats2half2_rn(r.x, r.y);
            __half2 h23 = __floats2half2_rn(r.z, r.w);
            *(__half2*)&out[(long)gr * 64 + c0] = h01;
            *(__half2*)&out[(long)gr * 64 + c0 + 2] = h23;
        } else {
            *(float4*)&out[(long)gr * 64 + c0] = r;
        }
    }
}

// ---------------- head ----------------

__global__ __launch_bounds__(256) void head_kernel(const float* __restrict__ z_user,
                                                   const float* __restrict__ z_movie,
                                                   const int* __restrict__ lrow,
                                                   const int* __restrict__ lcol,
                                                   const float* __restrict__ Wlin,
                                                   const float* __restrict__ blin,
                                                   float* __restrict__ out, int B) {
    int wave = (blockIdx.x * blockDim.x + threadIdx.x) >> 6;
    int lane = threadIdx.x & 63;
    int nw = (gridDim.x * blockDim.x) >> 6;
    for (int b = wave; b < B; b += nw) {
        int r = lrow[b], c = lcol[b];
        float zu = z_user[(long)r * 64 + lane];
        float zm = z_movie[(long)c * 64 + lane];
        float p0 = zu * Wlin[lane * 2 + 0] + zm * Wlin[(64 + lane) * 2 + 0];
        float p1 = zu * Wlin[lane * 2 + 1] + zm * Wlin[(64 + lane) * 2 + 1];
        for (int s = 32; s; s >>= 1) {
            p0 += __shfl_xor(p0, s, 64);
            p1 += __shfl_xor(p1, s, 64);
        }
        if (lane == 0) {
            float m = p0 + blin[0];
            float x = p1 + blin[1];
            float sp = fmaxf(x, 0.f) + log1pf(expf(-fabsf(x)));
            out[b] = m;
            out[B + b] = sp + 1e-6f;
        }
    }
}

// ---------------- launch ----------------

extern "C" void kernel_launch(void* const* d_in, const int* in_sizes, int n_in,
                              void* d_out, int out_size, void* d_ws, size_t ws_size,
                              hipStream_t stream) {
    const float* x_user  = (const float*)d_in[0];
    const float* x_movie = (const float*)d_in[1];
    const int* src_um = (const int*)d_in[2];
    const int* dst_um = (const int*)d_in[3];
    const int* src_mu = (const int*)d_in[4];
    const int* dst_mu = (const int*)d_in[5];
    const int* lrow = (const int*)d_in[6];
    const int* lcol = (const int*)d_in[7];
    const float* W1_um_l = (const float*)d_in[8];
    const float* b1_um   = (const float*)d_in[9];
    const float* W1_um_r = (const float*)d_in[10];
    const float* W1_mu_l = (const float*)d_in[11];
    const float* b1_mu   = (const float*)d_in[12];
    const float* W1_mu_r = (const float*)d_in[13];
    const float* W2_um_l = (const float*)d_in[14];
    const float* b2_um   = (const float*)d_in[15];
    const float* W2_um_r = (const float*)d_in[16];
    const float* W2_mu_l = (const float*)d_in[17];
    const float* b2_mu   = (const float*)d_in[18];
    const float* W2_mu_r = (const float*)d_in[19];
    const float* W_lin   = (const float*)d_in[20];
    const float* b_lin   = (const float*)d_in[21];
    float* out = (float*)d_out;

    const int E  = in_sizes[2];
    const int B  = in_sizes[6];
    const int NU = in_sizes[0] / 32;   // 100000
    const int NM = in_sizes[1] / 64;   // 20000

    char* wsp = (char*)d_ws;
    size_t o = 0;
    auto alloc = [&](size_t bytes) {
        size_t p = o;
        o += (bytes + 255) & ~(size_t)255;
        return (void*)(wsp + p);
    };
    int* off_um = (int*)alloc((size_t)(NM + 1) * 4);
    int* off_mu = (int*)alloc((size_t)(NU + 1) * 4);
    int* btot   = (int*)alloc((NBALL) * 4);
    int* boff   = (int*)alloc((NBALL + 1) * 4);
    int* csr_um = (int*)alloc((size_t)E * 4);
    int* csr_mu = (int*)alloc((size_t)E * 4);
    float* A_m  = (float*)alloc((size_t)NM * 64 * 4);   // movie mean / z_movie
    float* A_u  = (float*)alloc((size_t)NU * 64 * 4);   // user mean / z_user
    __half* Hh_m = (__half*)alloc((size_t)NM * 64 * 2); // h_movie fp16
    __half* Hh_u = (__half*)alloc((size_t)NU * 64 * 2); // h_user fp16
    __half* xh_u = (__half*)alloc((size_t)NU * 32 * 2); // x_user fp16
    __half* xh_m = (__half*)alloc((size_t)NM * 64 * 2); // x_movie fp16
    (void)ws_size;

    // aliases: consumed before their hosts are first written
    int* tmp   = (int*)A_u;   // [2E] ints = 16 MB <= 25.6 MB; dead after scatter_csr
    int* histM = (int*)A_m;   // 353*256*4 = 362 KB; dead after partition2

    // 0) fp16 copies of input feature tables
    cast_half2<<<512, 256, 0, stream>>>(x_user, xh_u, NU * 32, x_movie, xh_m, NM * 64);

    // 1) CSR build (block-private radix partition)
    hist_part<<<NBLK, 1024, 0, stream>>>(dst_um, dst_mu, histM, E);
    bucket_totals<<<(NBALL + 3) / 4, 256, 0, stream>>>(histM, btot, NBALL);
    boff_scan<<<1, 256, 0, stream>>>(btot, boff, NBALL, off_um, NM, off_mu, NU, E);
    add_boff<<<352, 256, 0, stream>>>(histM, boff, NBALL * NBLK);
    partition2<<<NBLK, 1024, 0, stream>>>(src_um, dst_um, src_mu, dst_mu, histM, tmp, E);
    scatter_csr<128><<<NB_UM, 256, 0, stream>>>(tmp, boff, off_um, csr_um, NM, 0);
    scatter_csr<512><<<NB_MU, 256, 0, stream>>>(tmp, boff + NB_UM, off_mu, csr_mu, NU, E);

    // 2) layer 1
    agg_mean_h<32><<<(NM + 3) / 4, 256, 0, stream>>>(csr_um, off_um, xh_u, A_m, NM);
    dense_gemm<32, 64, true, float, __half><<<(NM + 63) / 64, 256, 0, stream>>>(
        A_m, x_movie, W1_um_l, W1_um_r, b1_um, Hh_m, NM);
    agg_mean_h<64><<<(NU + 3) / 4, 256, 0, stream>>>(csr_mu, off_mu, xh_m, A_u, NU);
    dense_gemm<64, 32, true, float, __half><<<(NU + 63) / 64, 256, 0, stream>>>(
        A_u, x_user, W1_mu_l, W1_mu_r, b1_mu, Hh_u, NU);

    // 3) layer 2 (dense in-place over the mean buffers; rows staged in LDS first)
    agg_mean_h<64><<<(NM + 3) / 4, 256, 0, stream>>>(csr_um, off_um, Hh_u, A_m, NM);
    dense_gemm<64, 64, false, __half, float><<<(NM + 63) / 64, 256, 0, stream>>>(
        A_m, Hh_m, W2_um_l, W2_um_r, b2_um, A_m, NM);
    agg_mean_h<64><<<(NU + 3) / 4, 256, 0, stream>>>(csr_mu, off_mu, Hh_m, A_u, NU);
    dense_gemm<64, 64, false, __half, float><<<(NU + 63) / 64, 256, 0, stream>>>(
        A_u, Hh_u, W2_mu_l, W2_mu_r, b2_mu, A_u, NU);

    // 4) head
    head_kernel<<<4096, 256, 0, stream>>>(A_u, A_m, lrow, lcol, W_lin, b_lin, out, B);
}

// Round 9
// 345.295 us; speedup vs baseline: 1.4755x; 1.4755x over previous
//
#include <hip/hip_runtime.h>
#include <hip/hip_bf16.h>
#include <hip/hip_fp16.h>
#include <type_traits>

// combined bucket space: um buckets width 128 -> 157; mu buckets width 512 -> 196
#define NB_UM 157
#define NB_MU 196
#define NBALL 353
#define NBLK 256

using f16x8 = __attribute__((ext_vector_type(8))) _Float16;
using f32x4 = __attribute__((ext_vector_type(4))) float;

// ---------------- cast fp32 -> fp16 tables ----------------

__global__ __launch_bounds__(256) void cast_half2(const float* __restrict__ a,
                                                  __half* __restrict__ ah, int na,
                                                  const float* __restrict__ b,
                                                  __half* __restrict__ bh, int nb) {
    int i = blockIdx.x * blockDim.x + threadIdx.x;
    int st = gridDim.x * blockDim.x;
    for (int k = i; k < na / 2; k += st) {
        float2 v = ((const float2*)a)[k];
        ((__half2*)ah)[k] = __floats2half2_rn(v.x, v.y);
    }
    for (int k = i; k < nb / 2; k += st) {
        float2 v = ((const float2*)b)[k];
        ((__half2*)bh)[k] = __floats2half2_rn(v.x, v.y);
    }
}

// ---------------- pass 1: per-(bucket,block) histogram ----------------

__global__ __launch_bounds__(1024) void hist_part(const int* __restrict__ dst_um,
                                                  const int* __restrict__ dst_mu,
                                                  int* __restrict__ histM, int E) {
    __shared__ int h[NBALL];
    for (int i = threadIdx.x; i < NBALL; i += 1024) h[i] = 0;
    __syncthreads();
    int blk = blockIdx.x;
    int chunk = (E + NBLK - 1) / NBLK;
    int s = blk * chunk, e = min(E, s + chunk);
    for (int i = s + threadIdx.x; i < e; i += 1024) {
        atomicAdd(&h[dst_um[i] >> 7], 1);
        atomicAdd(&h[NB_UM + (dst_mu[i] >> 9)], 1);
    }
    __syncthreads();
    for (int i = threadIdx.x; i < NBALL; i += 1024) histM[i * NBLK + blk] = h[i];
}

// ---------------- pass 2: per-bucket wave scan over blocks ----------------

__global__ __launch_bounds__(256) void bucket_totals(int* __restrict__ histM,
                                                     int* __restrict__ btot, int nball) {
    int w = (blockIdx.x * blockDim.x + threadIdx.x) >> 6;
    int lane = threadIdx.x & 63;
    if (w >= nball) return;
    int* row = histM + w * NBLK;
    int v[4];
    int s = 0;
#pragma unroll
    for (int i = 0; i < 4; i++) {
        int c = row[lane * 4 + i];
        v[i] = s;
        s += c;
    }
    int incl = s;
    for (int d = 1; d < 64; d <<= 1) {
        int y = __shfl_up(incl, d, 64);
        if (lane >= d) incl += y;
    }
    int excl = incl - s;
#pragma unroll
    for (int i = 0; i < 4; i++) row[lane * 4 + i] = excl + v[i];
    if (lane == 63) btot[w] = incl;
}

// ---------------- pass 3: scan bucket totals ----------------

__global__ __launch_bounds__(256) void boff_scan(const int* __restrict__ btot,
                                                 int* __restrict__ boff, int nball,
                                                 int* __restrict__ off_um, int NM,
                                                 int* __restrict__ off_mu, int NU, int E) {
    __shared__ int sdata[256];
    int t = threadIdx.x;
    int v[8];
    int sum = 0;
#pragma unroll
    for (int i = 0; i < 8; i++) {
        int idx = t * 8 + i;
        int c = (idx < nball) ? btot[idx] : 0;
        v[i] = sum;
        sum += c;
    }
    sdata[t] = sum;
    __syncthreads();
    for (int s = 1; s < 256; s <<= 1) {
        int y = (t >= s) ? sdata[t - s] : 0;
        __syncthreads();
        sdata[t] += y;
        __syncthreads();
    }
    int base = (t == 0) ? 0 : sdata[t - 1];
#pragma unroll
    for (int i = 0; i < 8; i++) {
        int idx = t * 8 + i;
        if (idx < nball) boff[idx] = base + v[i];
    }
    if (t == 0) {
        boff[nball] = 2 * E;
        off_um[NM] = E;
        off_mu[NU] = E;
    }
}

// ---------------- pass 4: finalize off_mat ----------------

__global__ __launch_bounds__(256) void add_boff(int* __restrict__ histM,
                                                const int* __restrict__ boff, int n) {
    int st = gridDim.x * blockDim.x;
    for (int i = blockIdx.x * blockDim.x + threadIdx.x; i < n; i += st)
        histM[i] += boff[i >> 8];  // NBLK==256
}

// ---------------- pass 5: partition (block-private cursors in LDS) ----------------

__global__ __launch_bounds__(1024) void partition2(const int* __restrict__ src_um,
                                                   const int* __restrict__ dst_um,
                                                   const int* __restrict__ src_mu,
                                                   const int* __restrict__ dst_mu,
                                                   const int* __restrict__ histM,
                                                   int* __restrict__ tmp, int E) {
    __shared__ int cur[NBALL];
    int blk = blockIdx.x;
    for (int i = threadIdx.x; i < NBALL; i += 1024) cur[i] = histM[i * NBLK + blk];
    __syncthreads();
    int chunk = (E + NBLK - 1) / NBLK;
    int s = blk * chunk, e = min(E, s + chunk);
    for (int i = s + threadIdx.x; i < e; i += 1024) {
        int d = dst_um[i];
        int p = atomicAdd(&cur[d >> 7], 1);
        tmp[p] = src_um[i] | ((d & 127) << 20);
        int d2 = dst_mu[i];
        int q = atomicAdd(&cur[NB_UM + (d2 >> 9)], 1);
        tmp[q] = src_mu[i] | ((d2 & 511) << 20);
    }
}

// ---------------- pass 6: per-bucket CSR scatter ----------------

template <int W>
__global__ __launch_bounds__(256) void scatter_csr(const int* __restrict__ tmp,
                                                   const int* __restrict__ boff,
                                                   int* __restrict__ off,
                                                   int* __restrict__ csr, int n, int sub) {
    constexpr int EPT = (W + 255) / 256;  // elems per thread for the scan
    __shared__ int lcnt[W];
    __shared__ int lcur[W];
    __shared__ int sdata[256];
    int b = blockIdx.x;
    int t = threadIdx.x;
    int s = boff[b], e = boff[b + 1];
    for (int j = t; j < W; j += 256) lcnt[j] = 0;
    __syncthreads();
    for (int i = s + t; i < e; i += 256) atomicAdd(&lcnt[tmp[i] >> 20], 1);
    __syncthreads();
    // parallel exclusive scan of lcnt -> lcur (+s)
    int v[EPT];
    int sum = 0;
#pragma unroll
    for (int i = 0; i < EPT; i++) {
        int idx = t * EPT + i;
        int c = (idx < W) ? lcnt[idx] : 0;
        v[i] = sum;
        sum += c;
    }
    sdata[t] = sum;
    __syncthreads();
    for (int d = 1; d < 256; d <<= 1) {
        int y = (t >= d) ? sdata[t - d] : 0;
        __syncthreads();
        sdata[t] += y;
        __syncthreads();
    }
    int base = (t == 0) ? 0 : sdata[t - 1];
#pragma unroll
    for (int i = 0; i < EPT; i++) {
        int idx = t * EPT + i;
        if (idx < W) lcur[idx] = s + base + v[i];
    }
    __syncthreads();
    int rowbase = b * W;
    for (int j = t; j < W; j += 256)
        if (rowbase + j < n) off[rowbase + j] = lcur[j] - sub;
    __syncthreads();
    for (int i = s + t; i < e; i += 256) {
        int vv = tmp[i];
        int p = atomicAdd(&lcur[vv >> 20], 1);
        csr[p - sub] = vv & 0xFFFFF;
    }
}

// ---------------- segment mean (fp16 gather, one wave per dst row) ----------------

__device__ __forceinline__ void acc8(float* a, uint4 r) {
    const __half2* h = reinterpret_cast<const __half2*>(&r);
#pragma unroll
    for (int j = 0; j < 4; j++) {
        float2 f = __half22float2(h[j]);
        a[2 * j] += f.x;
        a[2 * j + 1] += f.y;
    }
}

template <int D>
__global__ __launch_bounds__(256) void agg_mean_h(const int* __restrict__ csr,
                                                  const int* __restrict__ off,
                                                  const __half* __restrict__ xh,
                                                  float* __restrict__ out, int nrows) {
    constexpr int LPE = D / 8;
    constexpr int GRP = 64 / LPE;
    int wave = (blockIdx.x * blockDim.x + threadIdx.x) >> 6;
    int lane = threadIdx.x & 63;
    int nwaves = (gridDim.x * blockDim.x) >> 6;
    int g = lane / LPE;
    int cl = lane % LPE;  // 8-col group
    for (int row = wave; row < nrows; row += nwaves) {
        int s = off[row], e = off[row + 1];
        float a[8] = {0.f, 0.f, 0.f, 0.f, 0.f, 0.f, 0.f, 0.f};
        for (int k = s + g; k < e; k += 2 * GRP) {
            int idx0 = csr[k];
            int k1 = k + GRP;
            int idx1 = (k1 < e) ? csr[k1] : -1;
            uint4 r0 = *(const uint4*)&xh[(long)idx0 * D + cl * 8];
            if (idx1 >= 0) {
                uint4 r1 = *(const uint4*)&xh[(long)idx1 * D + cl * 8];
                acc8(a, r0);
                acc8(a, r1);
            } else {
                acc8(a, r0);
            }
        }
        for (int m = LPE; m < 64; m <<= 1) {
#pragma unroll
            for (int j = 0; j < 8; j++) a[j] += __shfl_xor(a[j], m, 64);
        }
        if (g == 0) {
            float inv = 1.0f / fmaxf((float)(e - s), 1.0f);
            float4 r0 = make_float4(a[0] * inv, a[1] * inv, a[2] * inv, a[3] * inv);
            float4 r1 = make_float4(a[4] * inv, a[5] * inv, a[6] * inv, a[7] * inv);
            *(float4*)&out[(long)row * D + cl * 8] = r0;
            *(float4*)&out[(long)row * D + cl * 8 + 4] = r1;
        }
    }
}

// ---------------- dense via MFMA: out = act([mean|xd] @ [Wl;Wr] + b) ----------------
// 64x64 tile per block, 4 waves; wave w owns rows 16w..16w+15 x all 64 cols.
// A and W^T staged fp16 in LDS, stride K+8 halves (272B for K=128 -> 2-way conflicts only).
// mfma_f32_16x16x32_f16: A lane holds row lane&15, k=kk*32+8*(lane>>4)+j;
// B (=W^T row) lane holds col lane&15, same k. C/D: col=lane&15, row=(lane>>4)*4+reg (m89).

template <int Dm, int Dd, bool RELU, typename TX, typename TO>
__global__ __launch_bounds__(256) void dense_mfma(const float* __restrict__ mean,
                                                  const TX* __restrict__ xd,
                                                  const float* __restrict__ Wl,
                                                  const float* __restrict__ Wr,
                                                  const float* __restrict__ bias,
                                                  TO* __restrict__ out, int n) {
    constexpr int K = Dm + Dd;     // 96 or 128
    constexpr int SAP = K + 8;     // halves; (K+8)*2 bytes is a multiple of 16
    __shared__ __align__(16) _Float16 sA[64 * SAP];
    __shared__ __align__(16) _Float16 sWt[64 * SAP];
    __shared__ float sb[64];
    int t = threadIdx.x;
    int R0 = blockIdx.x * 64;

    // stage W transposed (fp16): sWt[col][k]
    for (int i = t; i < K * 16; i += 256) {
        int k = i >> 4, c = (i & 15) * 4;
        float4 v = (k < Dm) ? *(const float4*)&Wl[k * 64 + c]
                            : *(const float4*)&Wr[(k - Dm) * 64 + c];
        sWt[(c + 0) * SAP + k] = (_Float16)v.x;
        sWt[(c + 1) * SAP + k] = (_Float16)v.y;
        sWt[(c + 2) * SAP + k] = (_Float16)v.z;
        sWt[(c + 3) * SAP + k] = (_Float16)v.w;
    }
    if (t < 64) sb[t] = bias[t];
    // stage A (fp16): row r cols [0,Dm) from mean, [Dm,K) from xd
    constexpr int QR = K / 4;
    for (int i = t; i < 64 * QR; i += 256) {
        int r = i / QR, c = (i % QR) * 4;
        int gr = R0 + r;
        float4 v = make_float4(0.f, 0.f, 0.f, 0.f);
        if (gr < n) {
            if (c < Dm) {
                v = *(const float4*)&mean[(long)gr * Dm + c];
            } else {
                if constexpr (std::is_same<TX, __half>::value) {
                    const __half* p = &xd[(long)gr * Dd + (c - Dm)];
                    v = make_float4(__half2float(p[0]), __half2float(p[1]),
                                    __half2float(p[2]), __half2float(p[3]));
                } else {
                    v = *(const float4*)&xd[(long)gr * Dd + (c - Dm)];
                }
            }
        }
        _Float16* p = &sA[r * SAP + c];
        p[0] = (_Float16)v.x; p[1] = (_Float16)v.y;
        p[2] = (_Float16)v.z; p[3] = (_Float16)v.w;
    }
    __syncthreads();

    int w = t >> 6, lane = t & 63;
    int lr = lane & 15, lg = lane >> 4;  // 0..3
    f32x4 acc[4];
#pragma unroll
    for (int nt = 0; nt < 4; nt++) {
        float bb = sb[16 * nt + lr];
        acc[nt][0] = bb; acc[nt][1] = bb; acc[nt][2] = bb; acc[nt][3] = bb;
    }
    int arow = 16 * w + lr;
#pragma unroll
    for (int kk = 0; kk < K / 32; kk++) {
        int k0 = kk * 32 + 8 * lg;
        f16x8 a = *(const f16x8*)&sA[arow * SAP + k0];
#pragma unroll
        for (int nt = 0; nt < 4; nt++) {
            f16x8 b = *(const f16x8*)&sWt[(16 * nt + lr) * SAP + k0];
            acc[nt] = __builtin_amdgcn_mfma_f32_16x16x32_f16(a, b, acc[nt], 0, 0, 0);
        }
    }
#pragma unroll
    for (int nt = 0; nt < 4; nt++) {
#pragma unroll
        for (int r = 0; r < 4; r++) {
            int gr = R0 + 16 * w + lg * 4 + r;
            if (gr >= n) continue;
            float vv = acc[nt][r];
            if (RELU) vv = fmaxf(vv, 0.f);
            int gc = 16 * nt + lr;
            if constexpr (std::is_same<TO, __half>::value) {
                out[(long)gr * 64 + gc] = __float2half(vv);
            } else {
                out[(long)gr * 64 + gc] = vv;
            }
        }
    }
}

// ---------------- head ----------------

__global__ __launch_bounds__(256) void head_kernel(const float* __restrict__ z_user,
                                                   const float* __restrict__ z_movie,
                                                   const int* __restrict__ lrow,
                                                   const int* __restrict__ lcol,
                                                   const float* __restrict__ Wlin,
                                                   const float* __restrict__ blin,
                                                   float* __restrict__ out, int B) {
    int wave = (blockIdx.x * blockDim.x + threadIdx.x) >> 6;
    int lane = threadIdx.x & 63;
    int nw = (gridDim.x * blockDim.x) >> 6;
    for (int b = wave; b < B; b += nw) {
        int r = lrow[b], c = lcol[b];
        float zu = z_user[(long)r * 64 + lane];
        float zm = z_movie[(long)c * 64 + lane];
        float p0 = zu * Wlin[lane * 2 + 0] + zm * Wlin[(64 + lane) * 2 + 0];
        float p1 = zu * Wlin[lane * 2 + 1] + zm * Wlin[(64 + lane) * 2 + 1];
        for (int s = 32; s; s >>= 1) {
            p0 += __shfl_xor(p0, s, 64);
            p1 += __shfl_xor(p1, s, 64);
        }
        if (lane == 0) {
            float m = p0 + blin[0];
            float x = p1 + blin[1];
            float sp = fmaxf(x, 0.f) + log1pf(expf(-fabsf(x)));
            out[b] = m;
            out[B + b] = sp + 1e-6f;
        }
    }
}

// ---------------- launch ----------------

extern "C" void kernel_launch(void* const* d_in, const int* in_sizes, int n_in,
                              void* d_out, int out_size, void* d_ws, size_t ws_size,
                              hipStream_t stream) {
    const float* x_user  = (const float*)d_in[0];
    const float* x_movie = (const float*)d_in[1];
    const int* src_um = (const int*)d_in[2];
    const int* dst_um = (const int*)d_in[3];
    const int* src_mu = (const int*)d_in[4];
    const int* dst_mu = (const int*)d_in[5];
    const int* lrow = (const int*)d_in[6];
    const int* lcol = (const int*)d_in[7];
    const float* W1_um_l = (const float*)d_in[8];
    const float* b1_um   = (const float*)d_in[9];
    const float* W1_um_r = (const float*)d_in[10];
    const float* W1_mu_l = (const float*)d_in[11];
    const float* b1_mu   = (const float*)d_in[12];
    const float* W1_mu_r = (const float*)d_in[13];
    const float* W2_um_l = (const float*)d_in[14];
    const float* b2_um   = (const float*)d_in[15];
    const float* W2_um_r = (const float*)d_in[16];
    const float* W2_mu_l = (const float*)d_in[17];
    const float* b2_mu   = (const float*)d_in[18];
    const float* W2_mu_r = (const float*)d_in[19];
    const float* W_lin   = (const float*)d_in[20];
    const float* b_lin   = (const float*)d_in[21];
    float* out = (float*)d_out;

    const int E  = in_sizes[2];
    const int B  = in_sizes[6];
    const int NU = in_sizes[0] / 32;   // 100000
    const int NM = in_sizes[1] / 64;   // 20000

    char* wsp = (char*)d_ws;
    size_t o = 0;
    auto alloc = [&](size_t bytes) {
        size_t p = o;
        o += (bytes + 255) & ~(size_t)255;
        return (void*)(wsp + p);
    };
    int* off_um = (int*)alloc((size_t)(NM + 1) * 4);
    int* off_mu = (int*)alloc((size_t)(NU + 1) * 4);
    int* btot   = (int*)alloc((NBALL) * 4);
    int* boff   = (int*)alloc((NBALL + 1) * 4);
    int* csr_um = (int*)alloc((size_t)E * 4);
    int* csr_mu = (int*)alloc((size_t)E * 4);
    float* A_m  = (float*)alloc((size_t)NM * 64 * 4);   // movie mean / z_movie
    float* A_u  = (float*)alloc((size_t)NU * 64 * 4);   // user mean / z_user
    __half* Hh_m = (__half*)alloc((size_t)NM * 64 * 2); // h_movie fp16
    __half* Hh_u = (__half*)alloc((size_t)NU * 64 * 2); // h_user fp16
    __half* xh_u = (__half*)alloc((size_t)NU * 32 * 2); // x_user fp16
    __half* xh_m = (__half*)alloc((size_t)NM * 64 * 2); // x_movie fp16
    (void)ws_size;

    // aliases: consumed before their hosts are first written
    int* tmp   = (int*)A_u;   // [2E] ints = 16 MB <= 25.6 MB; dead after scatter_csr
    int* histM = (int*)A_m;   // 353*256*4 = 362 KB; dead after partition2

    // 0) fp16 copies of input feature tables
    cast_half2<<<512, 256, 0, stream>>>(x_user, xh_u, NU * 32, x_movie, xh_m, NM * 64);

    // 1) CSR build (block-private radix partition)
    hist_part<<<NBLK, 1024, 0, stream>>>(dst_um, dst_mu, histM, E);
    bucket_totals<<<(NBALL + 3) / 4, 256, 0, stream>>>(histM, btot, NBALL);
    boff_scan<<<1, 256, 0, stream>>>(btot, boff, NBALL, off_um, NM, off_mu, NU, E);
    add_boff<<<352, 256, 0, stream>>>(histM, boff, NBALL * NBLK);
    partition2<<<NBLK, 1024, 0, stream>>>(src_um, dst_um, src_mu, dst_mu, histM, tmp, E);
    scatter_csr<128><<<NB_UM, 256, 0, stream>>>(tmp, boff, off_um, csr_um, NM, 0);
    scatter_csr<512><<<NB_MU, 256, 0, stream>>>(tmp, boff + NB_UM, off_mu, csr_mu, NU, E);

    // 2) layer 1
    agg_mean_h<32><<<(NM + 3) / 4, 256, 0, stream>>>(csr_um, off_um, xh_u, A_m, NM);
    dense_mfma<32, 64, true, float, __half><<<(NM + 63) / 64, 256, 0, stream>>>(
        A_m, x_movie, W1_um_l, W1_um_r, b1_um, Hh_m, NM);
    agg_mean_h<64><<<(NU + 3) / 4, 256, 0, stream>>>(csr_mu, off_mu, xh_m, A_u, NU);
    dense_mfma<64, 32, true, float, __half><<<(NU + 63) / 64, 256, 0, stream>>>(
        A_u, x_user, W1_mu_l, W1_mu_r, b1_mu, Hh_u, NU);

    // 3) layer 2 (dense in-place over the mean buffers; rows staged in LDS first)
    agg_mean_h<64><<<(NM + 3) / 4, 256, 0, stream>>>(csr_um, off_um, Hh_u, A_m, NM);
    dense_mfma<64, 64, false, __half, float><<<(NM + 63) / 64, 256, 0, stream>>>(
        A_m, Hh_m, W2_um_l, W2_um_r, b2_um, A_m, NM);
    agg_mean_h<64><<<(NU + 3) / 4, 256, 0, stream>>>(csr_mu, off_mu, Hh_m, A_u, NU);
    dense_mfma<64, 64, false, __half, float><<<(NU + 63) / 64, 256, 0, stream>>>(
        A_u, Hh_u, W2_mu_l, W2_mu_r, b2_mu, A_u, NU);

    // 4) head
    head_kernel<<<4096, 256, 0, stream>>>(A_u, A_m, lrow, lcol, W_lin, b_lin, out, B);
}

// Round 10
// 311.260 us; speedup vs baseline: 1.6368x; 1.1093x over previous
//
#include <hip/hip_runtime.h>
#include <hip/hip_bf16.h>
#include <hip/hip_fp16.h>
#include <type_traits>

// combined bucket space: um buckets width 128 -> 157; mu buckets width 512 -> 196
#define NB_UM 157
#define NB_MU 196
#define NBALL 353
#define NBLK 256

using f16x8 = __attribute__((ext_vector_type(8))) _Float16;
using f32x4 = __attribute__((ext_vector_type(4))) float;

// ---------------- cast fp32 -> fp16 tables ----------------

__global__ __launch_bounds__(256) void cast_half2(const float* __restrict__ a,
                                                  __half* __restrict__ ah, int na,
                                                  const float* __restrict__ b,
                                                  __half* __restrict__ bh, int nb) {
    int i = blockIdx.x * blockDim.x + threadIdx.x;
    int st = gridDim.x * blockDim.x;
    for (int k = i; k < na / 2; k += st) {
        float2 v = ((const float2*)a)[k];
        ((__half2*)ah)[k] = __floats2half2_rn(v.x, v.y);
    }
    for (int k = i; k < nb / 2; k += st) {
        float2 v = ((const float2*)b)[k];
        ((__half2*)bh)[k] = __floats2half2_rn(v.x, v.y);
    }
}

// ---------------- pass 1: per-(bucket,block) histogram ----------------

__global__ __launch_bounds__(1024) void hist_part(const int* __restrict__ dst_um,
                                                  const int* __restrict__ dst_mu,
                                                  int* __restrict__ histM, int E) {
    __shared__ int h[NBALL];
    for (int i = threadIdx.x; i < NBALL; i += 1024) h[i] = 0;
    __syncthreads();
    int blk = blockIdx.x;
    int chunk = (E + NBLK - 1) / NBLK;
    int s = blk * chunk, e = min(E, s + chunk);
    for (int i = s + threadIdx.x; i < e; i += 1024) {
        atomicAdd(&h[dst_um[i] >> 7], 1);
        atomicAdd(&h[NB_UM + (dst_mu[i] >> 9)], 1);
    }
    __syncthreads();
    for (int i = threadIdx.x; i < NBALL; i += 1024) histM[i * NBLK + blk] = h[i];
}

// ---------------- pass 2: per-bucket wave scan over blocks ----------------

__global__ __launch_bounds__(256) void bucket_totals(int* __restrict__ histM,
                                                     int* __restrict__ btot, int nball) {
    int w = (blockIdx.x * blockDim.x + threadIdx.x) >> 6;
    int lane = threadIdx.x & 63;
    if (w >= nball) return;
    int* row = histM + w * NBLK;
    int v[4];
    int s = 0;
#pragma unroll
    for (int i = 0; i < 4; i++) {
        int c = row[lane * 4 + i];
        v[i] = s;
        s += c;
    }
    int incl = s;
    for (int d = 1; d < 64; d <<= 1) {
        int y = __shfl_up(incl, d, 64);
        if (lane >= d) incl += y;
    }
    int excl = incl - s;
#pragma unroll
    for (int i = 0; i < 4; i++) row[lane * 4 + i] = excl + v[i];
    if (lane == 63) btot[w] = incl;
}

// ---------------- pass 3: scan bucket totals ----------------

__global__ __launch_bounds__(256) void boff_scan(const int* __restrict__ btot,
                                                 int* __restrict__ boff, int nball,
                                                 int* __restrict__ off_um, int NM,
                                                 int* __restrict__ off_mu, int NU, int E) {
    __shared__ int sdata[256];
    int t = threadIdx.x;
    int v[8];
    int sum = 0;
#pragma unroll
    for (int i = 0; i < 8; i++) {
        int idx = t * 8 + i;
        int c = (idx < nball) ? btot[idx] : 0;
        v[i] = sum;
        sum += c;
    }
    sdata[t] = sum;
    __syncthreads();
    for (int s = 1; s < 256; s <<= 1) {
        int y = (t >= s) ? sdata[t - s] : 0;
        __syncthreads();
        sdata[t] += y;
        __syncthreads();
    }
    int base = (t == 0) ? 0 : sdata[t - 1];
#pragma unroll
    for (int i = 0; i < 8; i++) {
        int idx = t * 8 + i;
        if (idx < nball) boff[idx] = base + v[i];
    }
    if (t == 0) {
        boff[nball] = 2 * E;
        off_um[NM] = E;
        off_mu[NU] = E;
    }
}

// ---------------- pass 4: finalize off_mat ----------------

__global__ __launch_bounds__(256) void add_boff(int* __restrict__ histM,
                                                const int* __restrict__ boff, int n) {
    int st = gridDim.x * blockDim.x;
    for (int i = blockIdx.x * blockDim.x + threadIdx.x; i < n; i += st)
        histM[i] += boff[i >> 8];  // NBLK==256
}

// ---------------- pass 5: partition (block-private cursors in LDS) ----------------

__global__ __launch_bounds__(1024) void partition2(const int* __restrict__ src_um,
                                                   const int* __restrict__ dst_um,
                                                   const int* __restrict__ src_mu,
                                                   const int* __restrict__ dst_mu,
                                                   const int* __restrict__ histM,
                                                   int* __restrict__ tmp, int E) {
    __shared__ int cur[NBALL];
    int blk = blockIdx.x;
    for (int i = threadIdx.x; i < NBALL; i += 1024) cur[i] = histM[i * NBLK + blk];
    __syncthreads();
    int chunk = (E + NBLK - 1) / NBLK;
    int s = blk * chunk, e = min(E, s + chunk);
    for (int i = s + threadIdx.x; i < e; i += 1024) {
        int d = dst_um[i];
        int p = atomicAdd(&cur[d >> 7], 1);
        tmp[p] = src_um[i] | ((d & 127) << 20);
        int d2 = dst_mu[i];
        int q = atomicAdd(&cur[NB_UM + (d2 >> 9)], 1);
        tmp[q] = src_mu[i] | ((d2 & 511) << 20);
    }
}

// ---------------- pass 6: per-bucket CSR scatter ----------------

template <int W>
__global__ __launch_bounds__(256) void scatter_csr(const int* __restrict__ tmp,
                                                   const int* __restrict__ boff,
                                                   int* __restrict__ off,
                                                   int* __restrict__ csr, int n, int sub) {
    constexpr int EPT = (W + 255) / 256;  // elems per thread for the scan
    __shared__ int lcnt[W];
    __shared__ int lcur[W];
    __shared__ int sdata[256];
    int b = blockIdx.x;
    int t = threadIdx.x;
    int s = boff[b], e = boff[b + 1];
    for (int j = t; j < W; j += 256) lcnt[j] = 0;
    __syncthreads();
    for (int i = s + t; i < e; i += 256) atomicAdd(&lcnt[tmp[i] >> 20], 1);
    __syncthreads();
    // parallel exclusive scan of lcnt -> lcur (+s)
    int v[EPT];
    int sum = 0;
#pragma unroll
    for (int i = 0; i < EPT; i++) {
        int idx = t * EPT + i;
        int c = (idx < W) ? lcnt[idx] : 0;
        v[i] = sum;
        sum += c;
    }
    sdata[t] = sum;
    __syncthreads();
    for (int d = 1; d < 256; d <<= 1) {
        int y = (t >= d) ? sdata[t - d] : 0;
        __syncthreads();
        sdata[t] += y;
        __syncthreads();
    }
    int base = (t == 0) ? 0 : sdata[t - 1];
#pragma unroll
    for (int i = 0; i < EPT; i++) {
        int idx = t * EPT + i;
        if (idx < W) lcur[idx] = s + base + v[i];
    }
    __syncthreads();
    int rowbase = b * W;
    for (int j = t; j < W; j += 256)
        if (rowbase + j < n) off[rowbase + j] = lcur[j] - sub;
    __syncthreads();
    for (int i = s + t; i < e; i += 256) {
        int vv = tmp[i];
        int p = atomicAdd(&lcur[vv >> 20], 1);
        csr[p - sub] = vv & 0xFFFFF;
    }
}

// ---------------- segment mean (fp16 gather, one wave per dst row) ----------------

__device__ __forceinline__ void acc8(float* a, uint4 r) {
    const __half2* h = reinterpret_cast<const __half2*>(&r);
#pragma unroll
    for (int j = 0; j < 4; j++) {
        float2 f = __half22float2(h[j]);
        a[2 * j] += f.x;
        a[2 * j + 1] += f.y;
    }
}

template <int D>
__global__ __launch_bounds__(256) void agg_mean_h(const int* __restrict__ csr,
                                                  const int* __restrict__ off,
                                                  const __half* __restrict__ xh,
                                                  float* __restrict__ out, int nrows) {
    constexpr int LPE = D / 8;
    constexpr int GRP = 64 / LPE;
    int wave = (blockIdx.x * blockDim.x + threadIdx.x) >> 6;
    int lane = threadIdx.x & 63;
    int nwaves = (gridDim.x * blockDim.x) >> 6;
    int g = lane / LPE;
    int cl = lane % LPE;  // 8-col group
    for (int row = wave; row < nrows; row += nwaves) {
        int s = off[row], e = off[row + 1];
        float a[8] = {0.f, 0.f, 0.f, 0.f, 0.f, 0.f, 0.f, 0.f};
        for (int k = s + g; k < e; k += 2 * GRP) {
            int idx0 = csr[k];
            int k1 = k + GRP;
            int idx1 = (k1 < e) ? csr[k1] : -1;
            uint4 r0 = *(const uint4*)&xh[(long)idx0 * D + cl * 8];
            if (idx1 >= 0) {
                uint4 r1 = *(const uint4*)&xh[(long)idx1 * D + cl * 8];
                acc8(a, r0);
                acc8(a, r1);
            } else {
                acc8(a, r0);
            }
        }
        for (int m = LPE; m < 64; m <<= 1) {
#pragma unroll
            for (int j = 0; j < 8; j++) a[j] += __shfl_xor(a[j], m, 64);
        }
        if (g == 0) {
            float inv = 1.0f / fmaxf((float)(e - s), 1.0f);
            float4 r0 = make_float4(a[0] * inv, a[1] * inv, a[2] * inv, a[3] * inv);
            float4 r1 = make_float4(a[4] * inv, a[5] * inv, a[6] * inv, a[7] * inv);
            *(float4*)&out[(long)row * D + cl * 8] = r0;
            *(float4*)&out[(long)row * D + cl * 8 + 4] = r1;
        }
    }
}

// ---------------- dense via MFMA: out = act([mean|xd] @ [Wl;Wr] + b) ----------------

template <int Dm, int Dd, bool RELU, typename TX, typename TO>
__global__ __launch_bounds__(256) void dense_mfma(const float* __restrict__ mean,
                                                  const TX* __restrict__ xd,
                                                  const float* __restrict__ Wl,
                                                  const float* __restrict__ Wr,
                                                  const float* __restrict__ bias,
                                                  TO* __restrict__ out, int n) {
    constexpr int K = Dm + Dd;     // 96 or 128
    constexpr int SAP = K + 8;     // halves; (K+8)*2 bytes is a multiple of 16
    __shared__ __align__(16) _Float16 sA[64 * SAP];
    __shared__ __align__(16) _Float16 sWt[64 * SAP];
    __shared__ float sb[64];
    int t = threadIdx.x;
    int R0 = blockIdx.x * 64;

    // stage W transposed (fp16): sWt[col][k]
    for (int i = t; i < K * 16; i += 256) {
        int k = i >> 4, c = (i & 15) * 4;
        float4 v = (k < Dm) ? *(const float4*)&Wl[k * 64 + c]
                            : *(const float4*)&Wr[(k - Dm) * 64 + c];
        sWt[(c + 0) * SAP + k] = (_Float16)v.x;
        sWt[(c + 1) * SAP + k] = (_Float16)v.y;
        sWt[(c + 2) * SAP + k] = (_Float16)v.z;
        sWt[(c + 3) * SAP + k] = (_Float16)v.w;
    }
    if (t < 64) sb[t] = bias[t];
    // stage A (fp16): row r cols [0,Dm) from mean, [Dm,K) from xd
    constexpr int QR = K / 4;
    for (int i = t; i < 64 * QR; i += 256) {
        int r = i / QR, c = (i % QR) * 4;
        int gr = R0 + r;
        float4 v = make_float4(0.f, 0.f, 0.f, 0.f);
        if (gr < n) {
            if (c < Dm) {
                v = *(const float4*)&mean[(long)gr * Dm + c];
            } else {
                if constexpr (std::is_same<TX, __half>::value) {
                    const __half* p = &xd[(long)gr * Dd + (c - Dm)];
                    v = make_float4(__half2float(p[0]), __half2float(p[1]),
                                    __half2float(p[2]), __half2float(p[3]));
                } else {
                    v = *(const float4*)&xd[(long)gr * Dd + (c - Dm)];
                }
            }
        }
        _Float16* p = &sA[r * SAP + c];
        p[0] = (_Float16)v.x; p[1] = (_Float16)v.y;
        p[2] = (_Float16)v.z; p[3] = (_Float16)v.w;
    }
    __syncthreads();

    int w = t >> 6, lane = t & 63;
    int lr = lane & 15, lg = lane >> 4;  // 0..3
    f32x4 acc[4];
#pragma unroll
    for (int nt = 0; nt < 4; nt++) {
        float bb = sb[16 * nt + lr];
        acc[nt][0] = bb; acc[nt][1] = bb; acc[nt][2] = bb; acc[nt][3] = bb;
    }
    int arow = 16 * w + lr;
#pragma unroll
    for (int kk = 0; kk < K / 32; kk++) {
        int k0 = kk * 32 + 8 * lg;
        f16x8 a = *(const f16x8*)&sA[arow * SAP + k0];
#pragma unroll
        for (int nt = 0; nt < 4; nt++) {
            f16x8 b = *(const f16x8*)&sWt[(16 * nt + lr) * SAP + k0];
            acc[nt] = __builtin_amdgcn_mfma_f32_16x16x32_f16(a, b, acc[nt], 0, 0, 0);
        }
    }
#pragma unroll
    for (int nt = 0; nt < 4; nt++) {
#pragma unroll
        for (int r = 0; r < 4; r++) {
            int gr = R0 + 16 * w + lg * 4 + r;
            if (gr >= n) continue;
            float vv = acc[nt][r];
            if (RELU) vv = fmaxf(vv, 0.f);
            int gc = 16 * nt + lr;
            if constexpr (std::is_same<TO, __half>::value) {
                out[(long)gr * 64 + gc] = __float2half(vv);
            } else {
                out[(long)gr * 64 + gc] = vv;
            }
        }
    }
}

// ---------------- head projections: p[r] = z[r] . Wseg + (blin if addb) ----------------
// 16 lanes per row, 4 rows per wave per iteration.

__global__ __launch_bounds__(256) void proj_kernel(const float* __restrict__ z,
                                                   const float* __restrict__ Wlin,
                                                   int woff, const float* __restrict__ blin,
                                                   int addb, float2* __restrict__ p, int n) {
    __shared__ float sW0[64], sW1[64];
    int t = threadIdx.x;
    if (t < 64) {
        sW0[t] = Wlin[(woff + t) * 2 + 0];
        sW1[t] = Wlin[(woff + t) * 2 + 1];
    }
    __syncthreads();
    float b0 = addb ? blin[0] : 0.f;
    float b1 = addb ? blin[1] : 0.f;
    int lane = t & 63;
    int w = t >> 6;
    int lr = lane & 15, q = lane >> 4;  // lr: col quad, q: row in quad
    int row = blockIdx.x * 16 + w * 4 + q;
    if (row >= n) return;
    float4 zv = *(const float4*)&z[(long)row * 64 + lr * 4];
    float p0 = zv.x * sW0[lr * 4] + zv.y * sW0[lr * 4 + 1] + zv.z * sW0[lr * 4 + 2] + zv.w * sW0[lr * 4 + 3];
    float p1 = zv.x * sW1[lr * 4] + zv.y * sW1[lr * 4 + 1] + zv.z * sW1[lr * 4 + 2] + zv.w * sW1[lr * 4 + 3];
#pragma unroll
    for (int m = 1; m < 16; m <<= 1) {
        p0 += __shfl_xor(p0, m, 64);
        p1 += __shfl_xor(p1, m, 64);
    }
    if (lr == 0) p[row] = make_float2(p0 + b0, p1 + b1);
}

// ---------------- head: two 8B gathers + softplus per label ----------------

__global__ __launch_bounds__(256) void head_gather(const float2* __restrict__ pu,
                                                   const float2* __restrict__ pm,
                                                   const int* __restrict__ lrow,
                                                   const int* __restrict__ lcol,
                                                   float* __restrict__ out, int B) {
    int i = blockIdx.x * blockDim.x + threadIdx.x;
    int st = gridDim.x * blockDim.x;
    for (int b = i; b < B; b += st) {
        float2 a = pu[lrow[b]];
        float2 d = pm[lcol[b]];
        float m = a.x + d.x;
        float x = a.y + d.y;
        float sp = fmaxf(x, 0.f) + log1pf(expf(-fabsf(x)));
        out[b] = m;
        out[B + b] = sp + 1e-6f;
    }
}

// ---------------- launch ----------------

extern "C" void kernel_launch(void* const* d_in, const int* in_sizes, int n_in,
                              void* d_out, int out_size, void* d_ws, size_t ws_size,
                              hipStream_t stream) {
    const float* x_user  = (const float*)d_in[0];
    const float* x_movie = (const float*)d_in[1];
    const int* src_um = (const int*)d_in[2];
    const int* dst_um = (const int*)d_in[3];
    const int* src_mu = (const int*)d_in[4];
    const int* dst_mu = (const int*)d_in[5];
    const int* lrow = (const int*)d_in[6];
    const int* lcol = (const int*)d_in[7];
    const float* W1_um_l = (const float*)d_in[8];
    const float* b1_um   = (const float*)d_in[9];
    const float* W1_um_r = (const float*)d_in[10];
    const float* W1_mu_l = (const float*)d_in[11];
    const float* b1_mu   = (const float*)d_in[12];
    const float* W1_mu_r = (const float*)d_in[13];
    const float* W2_um_l = (const float*)d_in[14];
    const float* b2_um   = (const float*)d_in[15];
    const float* W2_um_r = (const float*)d_in[16];
    const float* W2_mu_l = (const float*)d_in[17];
    const float* b2_mu   = (const float*)d_in[18];
    const float* W2_mu_r = (const float*)d_in[19];
    const float* W_lin   = (const float*)d_in[20];
    const float* b_lin   = (const float*)d_in[21];
    float* out = (float*)d_out;

    const int E  = in_sizes[2];
    const int B  = in_sizes[6];
    const int NU = in_sizes[0] / 32;   // 100000
    const int NM = in_sizes[1] / 64;   // 20000

    char* wsp = (char*)d_ws;
    size_t o = 0;
    auto alloc = [&](size_t bytes) {
        size_t p = o;
        o += (bytes + 255) & ~(size_t)255;
        return (void*)(wsp + p);
    };
    int* off_um = (int*)alloc((size_t)(NM + 1) * 4);
    int* off_mu = (int*)alloc((size_t)(NU + 1) * 4);
    int* btot   = (int*)alloc((NBALL) * 4);
    int* boff   = (int*)alloc((NBALL + 1) * 4);
    int* csr_um = (int*)alloc((size_t)E * 4);
    int* csr_mu = (int*)alloc((size_t)E * 4);
    float* A_m  = (float*)alloc((size_t)NM * 64 * 4);   // movie mean / z_movie
    float* A_u  = (float*)alloc((size_t)NU * 64 * 4);   // user mean / z_user
    __half* Hh_m = (__half*)alloc((size_t)NM * 64 * 2); // h_movie fp16
    __half* Hh_u = (__half*)alloc((size_t)NU * 64 * 2); // h_user fp16
    __half* xh_u = (__half*)alloc((size_t)NU * 32 * 2); // x_user fp16
    __half* xh_m = (__half*)alloc((size_t)NM * 64 * 2); // x_movie fp16
    float2* pu  = (float2*)alloc((size_t)NU * 8);       // user head projection
    float2* pm  = (float2*)alloc((size_t)NM * 8);       // movie head projection
    (void)ws_size;

    // aliases: consumed before their hosts are first written
    int* tmp   = (int*)A_u;   // [2E] ints = 16 MB <= 25.6 MB; dead after scatter_csr
    int* histM = (int*)A_m;   // 353*256*4 = 362 KB; dead after partition2

    // 0) fp16 copies of input feature tables
    cast_half2<<<512, 256, 0, stream>>>(x_user, xh_u, NU * 32, x_movie, xh_m, NM * 64);

    // 1) CSR build (block-private radix partition)
    hist_part<<<NBLK, 1024, 0, stream>>>(dst_um, dst_mu, histM, E);
    bucket_totals<<<(NBALL + 3) / 4, 256, 0, stream>>>(histM, btot, NBALL);
    boff_scan<<<1, 256, 0, stream>>>(btot, boff, NBALL, off_um, NM, off_mu, NU, E);
    add_boff<<<352, 256, 0, stream>>>(histM, boff, NBALL * NBLK);
    partition2<<<NBLK, 1024, 0, stream>>>(src_um, dst_um, src_mu, dst_mu, histM, tmp, E);
    scatter_csr<128><<<NB_UM, 256, 0, stream>>>(tmp, boff, off_um, csr_um, NM, 0);
    scatter_csr<512><<<NB_MU, 256, 0, stream>>>(tmp, boff + NB_UM, off_mu, csr_mu, NU, E);

    // 2) layer 1
    agg_mean_h<32><<<(NM + 3) / 4, 256, 0, stream>>>(csr_um, off_um, xh_u, A_m, NM);
    dense_mfma<32, 64, true, float, __half><<<(NM + 63) / 64, 256, 0, stream>>>(
        A_m, x_movie, W1_um_l, W1_um_r, b1_um, Hh_m, NM);
    agg_mean_h<64><<<(NU + 3) / 4, 256, 0, stream>>>(csr_mu, off_mu, xh_m, A_u, NU);
    dense_mfma<64, 32, true, float, __half><<<(NU + 63) / 64, 256, 0, stream>>>(
        A_u, x_user, W1_mu_l, W1_mu_r, b1_mu, Hh_u, NU);

    // 3) layer 2 (dense in-place over the mean buffers; rows staged in LDS first)
    agg_mean_h<64><<<(NM + 3) / 4, 256, 0, stream>>>(csr_um, off_um, Hh_u, A_m, NM);
    dense_mfma<64, 64, false, __half, float><<<(NM + 63) / 64, 256, 0, stream>>>(
        A_m, Hh_m, W2_um_l, W2_um_r, b2_um, A_m, NM);
    agg_mean_h<64><<<(NU + 3) / 4, 256, 0, stream>>>(csr_mu, off_mu, Hh_m, A_u, NU);
    dense_mfma<64, 64, false, __half, float><<<(NU + 63) / 64, 256, 0, stream>>>(
        A_u, Hh_u, W2_mu_l, W2_mu_r, b2_mu, A_u, NU);

    // 4) head: project z to 2 dims per node, then gather per label
    proj_kernel<<<(NU + 15) / 16, 256, 0, stream>>>(A_u, W_lin, 0, b_lin, 1, pu, NU);
    proj_kernel<<<(NM + 15) / 16, 256, 0, stream>>>(A_m, W_lin, 64, b_lin, 0, pm, NM);
    head_gather<<<1024, 256, 0, stream>>>(pu, pm, lrow, lcol, out, B);
}

// Round 11
// 270.153 us; speedup vs baseline: 1.8859x; 1.1522x over previous
//
#include <hip/hip_runtime.h>
#include <hip/hip_bf16.h>
#include <hip/hip_fp16.h>
#include <type_traits>

// combined bucket space: um buckets width 128 -> 157; mu buckets width 512 -> 196
#define NB_UM 157
#define NB_MU 196
#define NBALL 353
#define NBLK 256

using f16x8 = __attribute__((ext_vector_type(8))) _Float16;
using f32x4 = __attribute__((ext_vector_type(4))) float;

// ---------------- cast fp32 -> fp16 tables ----------------

__global__ __launch_bounds__(256) void cast_half2(const float* __restrict__ a,
                                                  __half* __restrict__ ah, int na,
                                                  const float* __restrict__ b,
                                                  __half* __restrict__ bh, int nb) {
    int i = blockIdx.x * blockDim.x + threadIdx.x;
    int st = gridDim.x * blockDim.x;
    for (int k = i; k < na / 2; k += st) {
        float2 v = ((const float2*)a)[k];
        ((__half2*)ah)[k] = __floats2half2_rn(v.x, v.y);
    }
    for (int k = i; k < nb / 2; k += st) {
        float2 v = ((const float2*)b)[k];
        ((__half2*)bh)[k] = __floats2half2_rn(v.x, v.y);
    }
}

// ---------------- pass 1: per-(bucket,block) histogram ----------------

__global__ __launch_bounds__(1024) void hist_part(const int* __restrict__ dst_um,
                                                  const int* __restrict__ dst_mu,
                                                  int* __restrict__ histM, int E) {
    __shared__ int h[NBALL];
    for (int i = threadIdx.x; i < NBALL; i += 1024) h[i] = 0;
    __syncthreads();
    int blk = blockIdx.x;
    int chunk = (E + NBLK - 1) / NBLK;
    int s = blk * chunk, e = min(E, s + chunk);
    for (int i = s + threadIdx.x; i < e; i += 1024) {
        atomicAdd(&h[dst_um[i] >> 7], 1);
        atomicAdd(&h[NB_UM + (dst_mu[i] >> 9)], 1);
    }
    __syncthreads();
    for (int i = threadIdx.x; i < NBALL; i += 1024) histM[i * NBLK + blk] = h[i];
}

// ---------------- pass 2: per-bucket wave scan over blocks ----------------

__global__ __launch_bounds__(256) void bucket_totals(int* __restrict__ histM,
                                                     int* __restrict__ btot, int nball) {
    int w = (blockIdx.x * blockDim.x + threadIdx.x) >> 6;
    int lane = threadIdx.x & 63;
    if (w >= nball) return;
    int* row = histM + w * NBLK;
    int v[4];
    int s = 0;
#pragma unroll
    for (int i = 0; i < 4; i++) {
        int c = row[lane * 4 + i];
        v[i] = s;
        s += c;
    }
    int incl = s;
    for (int d = 1; d < 64; d <<= 1) {
        int y = __shfl_up(incl, d, 64);
        if (lane >= d) incl += y;
    }
    int excl = incl - s;
#pragma unroll
    for (int i = 0; i < 4; i++) row[lane * 4 + i] = excl + v[i];
    if (lane == 63) btot[w] = incl;
}

// ---------------- pass 3: scan bucket totals ----------------

__global__ __launch_bounds__(256) void boff_scan(const int* __restrict__ btot,
                                                 int* __restrict__ boff, int nball,
                                                 int* __restrict__ off_um, int NM,
                                                 int* __restrict__ off_mu, int NU, int E) {
    __shared__ int sdata[256];
    int t = threadIdx.x;
    int v[8];
    int sum = 0;
#pragma unroll
    for (int i = 0; i < 8; i++) {
        int idx = t * 8 + i;
        int c = (idx < nball) ? btot[idx] : 0;
        v[i] = sum;
        sum += c;
    }
    sdata[t] = sum;
    __syncthreads();
    for (int s = 1; s < 256; s <<= 1) {
        int y = (t >= s) ? sdata[t - s] : 0;
        __syncthreads();
        sdata[t] += y;
        __syncthreads();
    }
    int base = (t == 0) ? 0 : sdata[t - 1];
#pragma unroll
    for (int i = 0; i < 8; i++) {
        int idx = t * 8 + i;
        if (idx < nball) boff[idx] = base + v[i];
    }
    if (t == 0) {
        boff[nball] = 2 * E;
        off_um[NM] = E;
        off_mu[NU] = E;
    }
}

// ---------------- pass 4: finalize off_mat ----------------

__global__ __launch_bounds__(256) void add_boff(int* __restrict__ histM,
                                                const int* __restrict__ boff, int n) {
    int st = gridDim.x * blockDim.x;
    for (int i = blockIdx.x * blockDim.x + threadIdx.x; i < n; i += st)
        histM[i] += boff[i >> 8];  // NBLK==256
}

// ---------------- pass 5: partition (block-private cursors in LDS) ----------------

__global__ __launch_bounds__(1024) void partition2(const int* __restrict__ src_um,
                                                   const int* __restrict__ dst_um,
                                                   const int* __restrict__ src_mu,
                                                   const int* __restrict__ dst_mu,
                                                   const int* __restrict__ histM,
                                                   int* __restrict__ tmp, int E) {
    __shared__ int cur[NBALL];
    int blk = blockIdx.x;
    for (int i = threadIdx.x; i < NBALL; i += 1024) cur[i] = histM[i * NBLK + blk];
    __syncthreads();
    int chunk = (E + NBLK - 1) / NBLK;
    int s = blk * chunk, e = min(E, s + chunk);
    for (int i = s + threadIdx.x; i < e; i += 1024) {
        int d = dst_um[i];
        int p = atomicAdd(&cur[d >> 7], 1);
        tmp[p] = src_um[i] | ((d & 127) << 20);
        int d2 = dst_mu[i];
        int q = atomicAdd(&cur[NB_MU ? (NB_UM + (d2 >> 9)) : 0], 1);
        tmp[q] = src_mu[i] | ((d2 & 511) << 20);
    }
}

// ---------------- pass 6: per-bucket CSR scatter (1024 threads) ----------------

template <int W>
__global__ __launch_bounds__(1024) void scatter_csr(const int* __restrict__ tmp,
                                                    const int* __restrict__ boff,
                                                    int* __restrict__ off,
                                                    int* __restrict__ csr, int n, int sub) {
    __shared__ int lcnt[W];
    __shared__ int lcur[W];
    __shared__ int sdata[1024];
    int b = blockIdx.x;
    int t = threadIdx.x;
    int s = boff[b], e = boff[b + 1];
    for (int j = t; j < W; j += 1024) lcnt[j] = 0;
    __syncthreads();
    for (int i = s + t; i < e; i += 1024) atomicAdd(&lcnt[tmp[i] >> 20], 1);
    __syncthreads();
    // parallel exclusive scan of lcnt (W <= 1024: one elem per thread)
    int myc = (t < W) ? lcnt[t] : 0;
    sdata[t] = myc;
    __syncthreads();
    for (int d = 1; d < 1024; d <<= 1) {
        int y = (t >= d) ? sdata[t - d] : 0;
        __syncthreads();
        sdata[t] += y;
        __syncthreads();
    }
    if (t < W) lcur[t] = s + sdata[t] - myc;
    __syncthreads();
    int rowbase = b * W;
    for (int j = t; j < W; j += 1024)
        if (rowbase + j < n) off[rowbase + j] = lcur[j] - sub;
    __syncthreads();
    for (int i = s + t; i < e; i += 1024) {
        int vv = tmp[i];
        int p = atomicAdd(&lcur[vv >> 20], 1);
        csr[p - sub] = vv & 0xFFFFF;
    }
}

// ---------------- segment mean (fp16 gather, L-lane group per dst row) ----------------
// L = D/8 lanes per row; each lane owns 8 columns, accumulates privately. No shuffles.

__device__ __forceinline__ void acc8(float* a, uint4 r) {
    const __half2* h = reinterpret_cast<const __half2*>(&r);
#pragma unroll
    for (int j = 0; j < 4; j++) {
        float2 f = __half22float2(h[j]);
        a[2 * j] += f.x;
        a[2 * j + 1] += f.y;
    }
}

template <int D>
__global__ __launch_bounds__(256) void agg_mean_g(const int* __restrict__ csr,
                                                  const int* __restrict__ off,
                                                  const __half* __restrict__ xh,
                                                  float* __restrict__ out, int nrows) {
    constexpr int L = D / 8;  // lanes per row
    int gid = (blockIdx.x * blockDim.x + threadIdx.x) / L;
    int lg = threadIdx.x & (L - 1);
    int ngroups = (gridDim.x * blockDim.x) / L;
    int c8 = lg * 8;
    for (int row = gid; row < nrows; row += ngroups) {
        int s = off[row], e = off[row + 1];
        float a[8] = {0.f, 0.f, 0.f, 0.f, 0.f, 0.f, 0.f, 0.f};
        int k = s;
        for (; k + 4 <= e; k += 4) {
            int i0 = csr[k], i1 = csr[k + 1], i2 = csr[k + 2], i3 = csr[k + 3];
            uint4 r0 = *(const uint4*)&xh[(long)i0 * D + c8];
            uint4 r1 = *(const uint4*)&xh[(long)i1 * D + c8];
            uint4 r2 = *(const uint4*)&xh[(long)i2 * D + c8];
            uint4 r3 = *(const uint4*)&xh[(long)i3 * D + c8];
            acc8(a, r0); acc8(a, r1); acc8(a, r2); acc8(a, r3);
        }
        for (; k < e; ++k) {
            uint4 r0 = *(const uint4*)&xh[(long)csr[k] * D + c8];
            acc8(a, r0);
        }
        float inv = 1.0f / fmaxf((float)(e - s), 1.0f);
        float4 q0 = make_float4(a[0] * inv, a[1] * inv, a[2] * inv, a[3] * inv);
        float4 q1 = make_float4(a[4] * inv, a[5] * inv, a[6] * inv, a[7] * inv);
        *(float4*)&out[(long)row * D + c8] = q0;
        *(float4*)&out[(long)row * D + c8 + 4] = q1;
    }
}

// ---------------- dense via MFMA: out = act([mean|xd] @ [Wl;Wr] + b) ----------------

template <int Dm, int Dd, bool RELU, typename TX, typename TO>
__global__ __launch_bounds__(256) void dense_mfma(const float* __restrict__ mean,
                                                  const TX* __restrict__ xd,
                                                  const float* __restrict__ Wl,
                                                  const float* __restrict__ Wr,
                                                  const float* __restrict__ bias,
                                                  TO* __restrict__ out, int n) {
    constexpr int K = Dm + Dd;     // 96 or 128
    constexpr int SAP = K + 8;     // halves; (K+8)*2 bytes is a multiple of 16
    __shared__ __align__(16) _Float16 sA[64 * SAP];
    __shared__ __align__(16) _Float16 sWt[64 * SAP];
    __shared__ float sb[64];
    int t = threadIdx.x;
    int R0 = blockIdx.x * 64;

    // stage W transposed (fp16): sWt[col][k]
    for (int i = t; i < K * 16; i += 256) {
        int k = i >> 4, c = (i & 15) * 4;
        float4 v = (k < Dm) ? *(const float4*)&Wl[k * 64 + c]
                            : *(const float4*)&Wr[(k - Dm) * 64 + c];
        sWt[(c + 0) * SAP + k] = (_Float16)v.x;
        sWt[(c + 1) * SAP + k] = (_Float16)v.y;
        sWt[(c + 2) * SAP + k] = (_Float16)v.z;
        sWt[(c + 3) * SAP + k] = (_Float16)v.w;
    }
    if (t < 64) sb[t] = bias[t];
    // stage A (fp16): row r cols [0,Dm) from mean, [Dm,K) from xd
    constexpr int QR = K / 4;
    for (int i = t; i < 64 * QR; i += 256) {
        int r = i / QR, c = (i % QR) * 4;
        int gr = R0 + r;
        float4 v = make_float4(0.f, 0.f, 0.f, 0.f);
        if (gr < n) {
            if (c < Dm) {
                v = *(const float4*)&mean[(long)gr * Dm + c];
            } else {
                if constexpr (std::is_same<TX, __half>::value) {
                    const __half* p = &xd[(long)gr * Dd + (c - Dm)];
                    v = make_float4(__half2float(p[0]), __half2float(p[1]),
                                    __half2float(p[2]), __half2float(p[3]));
                } else {
                    v = *(const float4*)&xd[(long)gr * Dd + (c - Dm)];
                }
            }
        }
        _Float16* p = &sA[r * SAP + c];
        p[0] = (_Float16)v.x; p[1] = (_Float16)v.y;
        p[2] = (_Float16)v.z; p[3] = (_Float16)v.w;
    }
    __syncthreads();

    int w = t >> 6, lane = t & 63;
    int lr = lane & 15, lg = lane >> 4;  // 0..3
    f32x4 acc[4];
#pragma unroll
    for (int nt = 0; nt < 4; nt++) {
        float bb = sb[16 * nt + lr];
        acc[nt][0] = bb; acc[nt][1] = bb; acc[nt][2] = bb; acc[nt][3] = bb;
    }
    int arow = 16 * w + lr;
#pragma unroll
    for (int kk = 0; kk < K / 32; kk++) {
        int k0 = kk * 32 + 8 * lg;
        f16x8 a = *(const f16x8*)&sA[arow * SAP + k0];
#pragma unroll
        for (int nt = 0; nt < 4; nt++) {
            f16x8 b = *(const f16x8*)&sWt[(16 * nt + lr) * SAP + k0];
            acc[nt] = __builtin_amdgcn_mfma_f32_16x16x32_f16(a, b, acc[nt], 0, 0, 0);
        }
    }
#pragma unroll
    for (int nt = 0; nt < 4; nt++) {
#pragma unroll
        for (int r = 0; r < 4; r++) {
            int gr = R0 + 16 * w + lg * 4 + r;
            if (gr >= n) continue;
            float vv = acc[nt][r];
            if (RELU) vv = fmaxf(vv, 0.f);
            int gc = 16 * nt + lr;
            if constexpr (std::is_same<TO, __half>::value) {
                out[(long)gr * 64 + gc] = __float2half(vv);
            } else {
                out[(long)gr * 64 + gc] = vv;
            }
        }
    }
}

// ---------------- head projections: p[r] = z[r] . Wseg + (blin if addb) ----------------

__global__ __launch_bounds__(256) void proj_kernel(const float* __restrict__ z,
                                                   const float* __restrict__ Wlin,
                                                   int woff, const float* __restrict__ blin,
                                                   int addb, float2* __restrict__ p, int n) {
    __shared__ float sW0[64], sW1[64];
    int t = threadIdx.x;
    if (t < 64) {
        sW0[t] = Wlin[(woff + t) * 2 + 0];
        sW1[t] = Wlin[(woff + t) * 2 + 1];
    }
    __syncthreads();
    float b0 = addb ? blin[0] : 0.f;
    float b1 = addb ? blin[1] : 0.f;
    int lane = t & 63;
    int w = t >> 6;
    int lr = lane & 15, q = lane >> 4;
    int row = blockIdx.x * 16 + w * 4 + q;
    if (row >= n) return;
    float4 zv = *(const float4*)&z[(long)row * 64 + lr * 4];
    float p0 = zv.x * sW0[lr * 4] + zv.y * sW0[lr * 4 + 1] + zv.z * sW0[lr * 4 + 2] + zv.w * sW0[lr * 4 + 3];
    float p1 = zv.x * sW1[lr * 4] + zv.y * sW1[lr * 4 + 1] + zv.z * sW1[lr * 4 + 2] + zv.w * sW1[lr * 4 + 3];
#pragma unroll
    for (int m = 1; m < 16; m <<= 1) {
        p0 += __shfl_xor(p0, m, 64);
        p1 += __shfl_xor(p1, m, 64);
    }
    if (lr == 0) p[row] = make_float2(p0 + b0, p1 + b1);
}

// ---------------- head: two 8B gathers + softplus per label ----------------

__global__ __launch_bounds__(256) void head_gather(const float2* __restrict__ pu,
                                                   const float2* __restrict__ pm,
                                                   const int* __restrict__ lrow,
                                                   const int* __restrict__ lcol,
                                                   float* __restrict__ out, int B) {
    int i = blockIdx.x * blockDim.x + threadIdx.x;
    int st = gridDim.x * blockDim.x;
    for (int b = i; b < B; b += st) {
        float2 a = pu[lrow[b]];
        float2 d = pm[lcol[b]];
        float m = a.x + d.x;
        float x = a.y + d.y;
        float sp = fmaxf(x, 0.f) + log1pf(expf(-fabsf(x)));
        out[b] = m;
        out[B + b] = sp + 1e-6f;
    }
}

// ---------------- launch ----------------

extern "C" void kernel_launch(void* const* d_in, const int* in_sizes, int n_in,
                              void* d_out, int out_size, void* d_ws, size_t ws_size,
                              hipStream_t stream) {
    const float* x_user  = (const float*)d_in[0];
    const float* x_movie = (const float*)d_in[1];
    const int* src_um = (const int*)d_in[2];
    const int* dst_um = (const int*)d_in[3];
    const int* src_mu = (const int*)d_in[4];
    const int* dst_mu = (const int*)d_in[5];
    const int* lrow = (const int*)d_in[6];
    const int* lcol = (const int*)d_in[7];
    const float* W1_um_l = (const float*)d_in[8];
    const float* b1_um   = (const float*)d_in[9];
    const float* W1_um_r = (const float*)d_in[10];
    const float* W1_mu_l = (const float*)d_in[11];
    const float* b1_mu   = (const float*)d_in[12];
    const float* W1_mu_r = (const float*)d_in[13];
    const float* W2_um_l = (const float*)d_in[14];
    const float* b2_um   = (const float*)d_in[15];
    const float* W2_um_r = (const float*)d_in[16];
    const float* W2_mu_l = (const float*)d_in[17];
    const float* b2_mu   = (const float*)d_in[18];
    const float* W2_mu_r = (const float*)d_in[19];
    const float* W_lin   = (const float*)d_in[20];
    const float* b_lin   = (const float*)d_in[21];
    float* out = (float*)d_out;

    const int E  = in_sizes[2];
    const int B  = in_sizes[6];
    const int NU = in_sizes[0] / 32;   // 100000
    const int NM = in_sizes[1] / 64;   // 20000

    char* wsp = (char*)d_ws;
    size_t o = 0;
    auto alloc = [&](size_t bytes) {
        size_t p = o;
        o += (bytes + 255) & ~(size_t)255;
        return (void*)(wsp + p);
    };
    int* off_um = (int*)alloc((size_t)(NM + 1) * 4);
    int* off_mu = (int*)alloc((size_t)(NU + 1) * 4);
    int* btot   = (int*)alloc((NBALL) * 4);
    int* boff   = (int*)alloc((NBALL + 1) * 4);
    int* csr_um = (int*)alloc((size_t)E * 4);
    int* csr_mu = (int*)alloc((size_t)E * 4);
    float* A_m  = (float*)alloc((size_t)NM * 64 * 4);   // movie mean / z_movie
    float* A_u  = (float*)alloc((size_t)NU * 64 * 4);   // user mean / z_user
    __half* Hh_m = (__half*)alloc((size_t)NM * 64 * 2); // h_movie fp16
    __half* Hh_u = (__half*)alloc((size_t)NU * 64 * 2); // h_user fp16
    __half* xh_u = (__half*)alloc((size_t)NU * 32 * 2); // x_user fp16
    __half* xh_m = (__half*)alloc((size_t)NM * 64 * 2); // x_movie fp16
    float2* pu  = (float2*)alloc((size_t)NU * 8);       // user head projection
    float2* pm  = (float2*)alloc((size_t)NM * 8);       // movie head projection
    (void)ws_size;

    // aliases: consumed before their hosts are first written
    int* tmp   = (int*)A_u;   // [2E] ints = 16 MB <= 25.6 MB; dead after scatter_csr
    int* histM = (int*)A_m;   // 353*256*4 = 362 KB; dead after partition2

    // 0) fp16 copies of input feature tables
    cast_half2<<<512, 256, 0, stream>>>(x_user, xh_u, NU * 32, x_movie, xh_m, NM * 64);

    // 1) CSR build (block-private radix partition)
    hist_part<<<NBLK, 1024, 0, stream>>>(dst_um, dst_mu, histM, E);
    bucket_totals<<<(NBALL + 3) / 4, 256, 0, stream>>>(histM, btot, NBALL);
    boff_scan<<<1, 256, 0, stream>>>(btot, boff, NBALL, off_um, NM, off_mu, NU, E);
    add_boff<<<352, 256, 0, stream>>>(histM, boff, NBALL * NBLK);
    partition2<<<NBLK, 1024, 0, stream>>>(src_um, dst_um, src_mu, dst_mu, histM, tmp, E);
    scatter_csr<128><<<NB_UM, 1024, 0, stream>>>(tmp, boff, off_um, csr_um, NM, 0);
    scatter_csr<512><<<NB_MU, 1024, 0, stream>>>(tmp, boff + NB_UM, off_mu, csr_mu, NU, E);

    // 2) layer 1
    agg_mean_g<32><<<(NM * 4 + 255) / 256, 256, 0, stream>>>(csr_um, off_um, xh_u, A_m, NM);
    dense_mfma<32, 64, true, float, __half><<<(NM + 63) / 64, 256, 0, stream>>>(
        A_m, x_movie, W1_um_l, W1_um_r, b1_um, Hh_m, NM);
    agg_mean_g<64><<<(NU * 8 + 255) / 256, 256, 0, stream>>>(csr_mu, off_mu, xh_m, A_u, NU);
    dense_mfma<64, 32, true, float, __half><<<(NU + 63) / 64, 256, 0, stream>>>(
        A_u, x_user, W1_mu_l, W1_mu_r, b1_mu, Hh_u, NU);

    // 3) layer 2 (dense in-place over the mean buffers; rows staged in LDS first)
    agg_mean_g<64><<<(NM * 8 + 255) / 256, 256, 0, stream>>>(csr_um, off_um, Hh_u, A_m, NM);
    dense_mfma<64, 64, false, __half, float><<<(NM + 63) / 64, 256, 0, stream>>>(
        A_m, Hh_m, W2_um_l, W2_um_r, b2_um, A_m, NM);
    agg_mean_g<64><<<(NU * 8 + 255) / 256, 256, 0, stream>>>(csr_mu, off_mu, Hh_m, A_u, NU);
    dense_mfma<64, 64, false, __half, float><<<(NU + 63) / 64, 256, 0, stream>>>(
        A_u, Hh_u, W2_mu_l, W2_mu_r, b2_mu, A_u, NU);

    // 4) head: project z to 2 dims per node, then gather per label
    proj_kernel<<<(NU + 15) / 16, 256, 0, stream>>>(A_u, W_lin, 0, b_lin, 1, pu, NU);
    proj_kernel<<<(NM + 15) / 16, 256, 0, stream>>>(A_m, W_lin, 64, b_lin, 0, pm, NM);
    head_gather<<<1024, 256, 0, stream>>>(pu, pm, lrow, lcol, out, B);
}

// Round 13
// 262.219 us; speedup vs baseline: 1.9429x; 1.0303x over previous
//
#include <hip/hip_runtime.h>
#include <hip/hip_bf16.h>
#include <hip/hip_fp16.h>
#include <type_traits>

// combined bucket space: um buckets width 128 -> 157; mu buckets width 512 -> 196
#define NB_UM 157
#define NB_MU 196
#define NBALL 353
#define NBLK 256

using f16x8 = __attribute__((ext_vector_type(8))) _Float16;
using f32x4 = __attribute__((ext_vector_type(4))) float;

// ---------------- cast fp32 -> fp16 tables ----------------

__global__ __launch_bounds__(256) void cast_half2(const float* __restrict__ a,
                                                  __half* __restrict__ ah, int na,
                                                  const float* __restrict__ b,
                                                  __half* __restrict__ bh, int nb) {
    int i = blockIdx.x * blockDim.x + threadIdx.x;
    int st = gridDim.x * blockDim.x;
    for (int k = i; k < na / 2; k += st) {
        float2 v = ((const float2*)a)[k];
        ((__half2*)ah)[k] = __floats2half2_rn(v.x, v.y);
    }
    for (int k = i; k < nb / 2; k += st) {
        float2 v = ((const float2*)b)[k];
        ((__half2*)bh)[k] = __floats2half2_rn(v.x, v.y);
    }
}

// ---------------- pass 1: per-(bucket,block) histogram (int4 loads) ----------------

__global__ __launch_bounds__(1024) void hist_part(const int* __restrict__ dst_um,
                                                  const int* __restrict__ dst_mu,
                                                  int* __restrict__ histM, int E, int chunk) {
    __shared__ int h[NBALL];
    for (int i = threadIdx.x; i < NBALL; i += 1024) h[i] = 0;
    __syncthreads();
    int blk = blockIdx.x;
    int s = blk * chunk, e = min(E, s + chunk);
    if (s < e) {
        int n4 = (e - s) >> 2;
        const int4* du4 = (const int4*)(dst_um + s);
        const int4* dm4 = (const int4*)(dst_mu + s);
        for (int i = threadIdx.x; i < n4; i += 1024) {
            int4 d = du4[i];
            atomicAdd(&h[d.x >> 7], 1);
            atomicAdd(&h[d.y >> 7], 1);
            atomicAdd(&h[d.z >> 7], 1);
            atomicAdd(&h[d.w >> 7], 1);
            int4 m = dm4[i];
            atomicAdd(&h[NB_UM + (m.x >> 9)], 1);
            atomicAdd(&h[NB_UM + (m.y >> 9)], 1);
            atomicAdd(&h[NB_UM + (m.z >> 9)], 1);
            atomicAdd(&h[NB_UM + (m.w >> 9)], 1);
        }
        for (int i = s + (n4 << 2) + threadIdx.x; i < e; i += 1024) {
            atomicAdd(&h[dst_um[i] >> 7], 1);
            atomicAdd(&h[NB_UM + (dst_mu[i] >> 9)], 1);
        }
    }
    __syncthreads();
    for (int i = threadIdx.x; i < NBALL; i += 1024) histM[i * NBLK + blk] = h[i];
}

// ---------------- pass 2: per-bucket wave scan over blocks ----------------

__global__ __launch_bounds__(256) void bucket_totals(int* __restrict__ histM,
                                                     int* __restrict__ btot, int nball) {
    int w = (blockIdx.x * blockDim.x + threadIdx.x) >> 6;
    int lane = threadIdx.x & 63;
    if (w >= nball) return;
    int* row = histM + w * NBLK;
    int v[4];
    int s = 0;
#pragma unroll
    for (int i = 0; i < 4; i++) {
        int c = row[lane * 4 + i];
        v[i] = s;
        s += c;
    }
    int incl = s;
    for (int d = 1; d < 64; d <<= 1) {
        int y = __shfl_up(incl, d, 64);
        if (lane >= d) incl += y;
    }
    int excl = incl - s;
#pragma unroll
    for (int i = 0; i < 4; i++) row[lane * 4 + i] = excl + v[i];
    if (lane == 63) btot[w] = incl;
}

// ---------------- pass 3: scan bucket totals ----------------

__global__ __launch_bounds__(256) void boff_scan(const int* __restrict__ btot,
                                                 int* __restrict__ boff, int nball,
                                                 int* __restrict__ off_um, int NM,
                                                 int* __restrict__ off_mu, int NU, int E) {
    __shared__ int sdata[256];
    int t = threadIdx.x;
    int v[8];
    int sum = 0;
#pragma unroll
    for (int i = 0; i < 8; i++) {
        int idx = t * 8 + i;
        int c = (idx < nball) ? btot[idx] : 0;
        v[i] = sum;
        sum += c;
    }
    sdata[t] = sum;
    __syncthreads();
    for (int s = 1; s < 256; s <<= 1) {
        int y = (t >= s) ? sdata[t - s] : 0;
        __syncthreads();
        sdata[t] += y;
        __syncthreads();
    }
    int base = (t == 0) ? 0 : sdata[t - 1];
#pragma unroll
    for (int i = 0; i < 8; i++) {
        int idx = t * 8 + i;
        if (idx < nball) boff[idx] = base + v[i];
    }
    if (t == 0) {
        boff[nball] = 2 * E;
        off_um[NM] = E;
        off_mu[NU] = E;
    }
}

// ---------------- pass 4: partition (block-private cursors; cur = histM + boff) ----------------

__global__ __launch_bounds__(1024) void partition2(const int* __restrict__ src_um,
                                                   const int* __restrict__ dst_um,
                                                   const int* __restrict__ src_mu,
                                                   const int* __restrict__ dst_mu,
                                                   const int* __restrict__ histM,
                                                   const int* __restrict__ boff,
                                                   int* __restrict__ tmp, int E, int chunk) {
    __shared__ int cur[NBALL];
    int blk = blockIdx.x;
    for (int i = threadIdx.x; i < NBALL; i += 1024)
        cur[i] = histM[i * NBLK + blk] + boff[i];
    __syncthreads();
    int s = blk * chunk, e = min(E, s + chunk);
    if (s >= e) return;
    int n4 = (e - s) >> 2;
    const int4* su4 = (const int4*)(src_um + s);
    const int4* du4 = (const int4*)(dst_um + s);
    const int4* sm4 = (const int4*)(src_mu + s);
    const int4* dm4 = (const int4*)(dst_mu + s);
    for (int i = threadIdx.x; i < n4; i += 1024) {
        int4 sv = su4[i];
        int4 dv = du4[i];
        int p;
        p = atomicAdd(&cur[dv.x >> 7], 1); tmp[p] = sv.x | ((dv.x & 127) << 20);
        p = atomicAdd(&cur[dv.y >> 7], 1); tmp[p] = sv.y | ((dv.y & 127) << 20);
        p = atomicAdd(&cur[dv.z >> 7], 1); tmp[p] = sv.z | ((dv.z & 127) << 20);
        p = atomicAdd(&cur[dv.w >> 7], 1); tmp[p] = sv.w | ((dv.w & 127) << 20);
        int4 sv2 = sm4[i];
        int4 dv2 = dm4[i];
        p = atomicAdd(&cur[NB_UM + (dv2.x >> 9)], 1); tmp[p] = sv2.x | ((dv2.x & 511) << 20);
        p = atomicAdd(&cur[NB_UM + (dv2.y >> 9)], 1); tmp[p] = sv2.y | ((dv2.y & 511) << 20);
        p = atomicAdd(&cur[NB_UM + (dv2.z >> 9)], 1); tmp[p] = sv2.z | ((dv2.z & 511) << 20);
        p = atomicAdd(&cur[NB_UM + (dv2.w >> 9)], 1); tmp[p] = sv2.w | ((dv2.w & 511) << 20);
    }
    for (int i = s + (n4 << 2) + threadIdx.x; i < e; i += 1024) {
        int d = dst_um[i];
        int p = atomicAdd(&cur[d >> 7], 1);
        tmp[p] = src_um[i] | ((d & 127) << 20);
        int d2 = dst_mu[i];
        int q = atomicAdd(&cur[NB_UM + (d2 >> 9)], 1);
        tmp[q] = src_mu[i] | ((d2 & 511) << 20);
    }
}

// ---------------- pass 5: per-bucket CSR scatter, both sides in one grid ----------------

__global__ __launch_bounds__(1024) void scatter_both(const int* __restrict__ tmp,
                                                     const int* __restrict__ boff,
                                                     int* __restrict__ off_um,
                                                     int* __restrict__ csr_um, int NM,
                                                     int* __restrict__ off_mu,
                                                     int* __restrict__ csr_mu, int NU, int E) {
    __shared__ int lcnt[512];
    __shared__ int lcur[512];
    __shared__ int sdata[1024];
    int b = blockIdx.x;
    int um = (b < NB_UM);
    int W = um ? 128 : 512;
    int n = um ? NM : NU;
    int sub = um ? 0 : E;
    int* off = um ? off_um : off_mu;
    int* csr = um ? csr_um : csr_mu;
    int rowbase = (um ? b : (b - NB_UM)) * W;
    int t = threadIdx.x;
    int s = boff[b], e = boff[b + 1];
    for (int j = t; j < W; j += 1024) lcnt[j] = 0;
    __syncthreads();
    for (int i = s + t; i < e; i += 1024) atomicAdd(&lcnt[tmp[i] >> 20], 1);
    __syncthreads();
    int myc = (t < W) ? lcnt[t] : 0;
    sdata[t] = myc;
    __syncthreads();
    for (int d = 1; d < 1024; d <<= 1) {
        int y = (t >= d) ? sdata[t - d] : 0;
        __syncthreads();
        sdata[t] += y;
        __syncthreads();
    }
    if (t < W) lcur[t] = s + sdata[t] - myc;
    __syncthreads();
    for (int j = t; j < W; j += 1024)
        if (rowbase + j < n) off[rowbase + j] = lcur[j] - sub;
    __syncthreads();
    for (int i = s + t; i < e; i += 1024) {
        int vv = tmp[i];
        int p = atomicAdd(&lcur[vv >> 20], 1);
        csr[p - sub] = vv & 0xFFFFF;
    }
}

// ---------------- segment mean (fp16 gather, L-lane group per dst row) ----------------

__device__ __forceinline__ void acc8(float* a, uint4 r) {
    const __half2* h = reinterpret_cast<const __half2*>(&r);
#pragma unroll
    for (int j = 0; j < 4; j++) {
        float2 f = __half22float2(h[j]);
        a[2 * j] += f.x;
        a[2 * j + 1] += f.y;
    }
}

template <int D>
__global__ __launch_bounds__(256) void agg_mean_g(const int* __restrict__ csr,
                                                  const int* __restrict__ off,
                                                  const __half* __restrict__ xh,
                                                  float* __restrict__ out, int nrows) {
    constexpr int L = D / 8;  // lanes per row
    int gid = (blockIdx.x * blockDim.x + threadIdx.x) / L;
    int lg = threadIdx.x & (L - 1);
    int ngroups = (gridDim.x * blockDim.x) / L;
    int c8 = lg * 8;
    for (int row = gid; row < nrows; row += ngroups) {
        int s = off[row], e = off[row + 1];
        float a[8] = {0.f, 0.f, 0.f, 0.f, 0.f, 0.f, 0.f, 0.f};
        int k = s;
        for (; k + 4 <= e; k += 4) {
            int i0 = csr[k], i1 = csr[k + 1], i2 = csr[k + 2], i3 = csr[k + 3];
            uint4 r0 = *(const uint4*)&xh[(long)i0 * D + c8];
            uint4 r1 = *(const uint4*)&xh[(long)i1 * D + c8];
            uint4 r2 = *(const uint4*)&xh[(long)i2 * D + c8];
            uint4 r3 = *(const uint4*)&xh[(long)i3 * D + c8];
            acc8(a, r0); acc8(a, r1); acc8(a, r2); acc8(a, r3);
        }
        for (; k < e; ++k) {
            uint4 r0 = *(const uint4*)&xh[(long)csr[k] * D + c8];
            acc8(a, r0);
        }
        float inv = 1.0f / fmaxf((float)(e - s), 1.0f);
        float4 q0 = make_float4(a[0] * inv, a[1] * inv, a[2] * inv, a[3] * inv);
        float4 q1 = make_float4(a[4] * inv, a[5] * inv, a[6] * inv, a[7] * inv);
        *(float4*)&out[(long)row * D + c8] = q0;
        *(float4*)&out[(long)row * D + c8 + 4] = q1;
    }
}

// ---------------- dense via MFMA: out = act([mean|xd] @ [Wl;Wr] + b) ----------------
// R11-proven version (no fusion).

template <int Dm, int Dd, bool RELU, typename TX, typename TO>
__global__ __launch_bounds__(256) void dense_mfma(const float* __restrict__ mean,
                                                  const TX* __restrict__ xd,
                                                  const float* __restrict__ Wl,
                                                  const float* __restrict__ Wr,
                                                  const float* __restrict__ bias,
                                                  TO* __restrict__ out, int n) {
    constexpr int K = Dm + Dd;     // 96 or 128
    constexpr int SAP = K + 8;     // halves; (K+8)*2 bytes is a multiple of 16
    __shared__ __align__(16) _Float16 sA[64 * SAP];
    __shared__ __align__(16) _Float16 sWt[64 * SAP];
    __shared__ float sb[64];
    int t = threadIdx.x;
    int R0 = blockIdx.x * 64;

    // stage W transposed (fp16): sWt[col][k]
    for (int i = t; i < K * 16; i += 256) {
        int k = i >> 4, c = (i & 15) * 4;
        float4 v = (k < Dm) ? *(const float4*)&Wl[k * 64 + c]
                            : *(const float4*)&Wr[(k - Dm) * 64 + c];
        sWt[(c + 0) * SAP + k] = (_Float16)v.x;
        sWt[(c + 1) * SAP + k] = (_Float16)v.y;
        sWt[(c + 2) * SAP + k] = (_Float16)v.z;
        sWt[(c + 3) * SAP + k] = (_Float16)v.w;
    }
    if (t < 64) sb[t] = bias[t];
    // stage A (fp16): row r cols [0,Dm) from mean, [Dm,K) from xd
    constexpr int QR = K / 4;
    for (int i = t; i < 64 * QR; i += 256) {
        int r = i / QR, c = (i % QR) * 4;
        int gr = R0 + r;
        float4 v = make_float4(0.f, 0.f, 0.f, 0.f);
        if (gr < n) {
            if (c < Dm) {
                v = *(const float4*)&mean[(long)gr * Dm + c];
            } else {
                if constexpr (std::is_same<TX, __half>::value) {
                    const __half* p = &xd[(long)gr * Dd + (c - Dm)];
                    v = make_float4(__half2float(p[0]), __half2float(p[1]),
                                    __half2float(p[2]), __half2float(p[3]));
                } else {
                    v = *(const float4*)&xd[(long)gr * Dd + (c - Dm)];
                }
            }
        }
        _Float16* p = &sA[r * SAP + c];
        p[0] = (_Float16)v.x; p[1] = (_Float16)v.y;
        p[2] = (_Float16)v.z; p[3] = (_Float16)v.w;
    }
    __syncthreads();

    int w = t >> 6, lane = t & 63;
    int lr = lane & 15, lg = lane >> 4;  // 0..3
    f32x4 acc[4];
#pragma unroll
    for (int nt = 0; nt < 4; nt++) {
        float bb = sb[16 * nt + lr];
        acc[nt][0] = bb; acc[nt][1] = bb; acc[nt][2] = bb; acc[nt][3] = bb;
    }
    int arow = 16 * w + lr;
#pragma unroll
    for (int kk = 0; kk < K / 32; kk++) {
        int k0 = kk * 32 + 8 * lg;
        f16x8 a = *(const f16x8*)&sA[arow * SAP + k0];
#pragma unroll
        for (int nt = 0; nt < 4; nt++) {
            f16x8 b = *(const f16x8*)&sWt[(16 * nt + lr) * SAP + k0];
            acc[nt] = __builtin_amdgcn_mfma_f32_16x16x32_f16(a, b, acc[nt], 0, 0, 0);
        }
    }
#pragma unroll
    for (int nt = 0; nt < 4; nt++) {
#pragma unroll
        for (int r = 0; r < 4; r++) {
            int gr = R0 + 16 * w + lg * 4 + r;
            if (gr >= n) continue;
            float vv = acc[nt][r];
            if (RELU) vv = fmaxf(vv, 0.f);
            int gc = 16 * nt + lr;
            if constexpr (std::is_same<TO, __half>::value) {
                out[(long)gr * 64 + gc] = __float2half(vv);
            } else {
                out[(long)gr * 64 + gc] = vv;
            }
        }
    }
}

// ---------------- head projections: p[r] = z[r] . Wseg + (blin if addb) ----------------

__global__ __launch_bounds__(256) void proj_kernel(const float* __restrict__ z,
                                                   const float* __restrict__ Wlin,
                                                   int woff, const float* __restrict__ blin,
                                                   int addb, float2* __restrict__ p, int n) {
    __shared__ float sW0[64], sW1[64];
    int t = threadIdx.x;
    if (t < 64) {
        sW0[t] = Wlin[(woff + t) * 2 + 0];
        sW1[t] = Wlin[(woff + t) * 2 + 1];
    }
    __syncthreads();
    float b0 = addb ? blin[0] : 0.f;
    float b1 = addb ? blin[1] : 0.f;
    int lane = t & 63;
    int w = t >> 6;
    int lr = lane & 15, q = lane >> 4;
    int row = blockIdx.x * 16 + w * 4 + q;
    if (row >= n) return;
    float4 zv = *(const float4*)&z[(long)row * 64 + lr * 4];
    float p0 = zv.x * sW0[lr * 4] + zv.y * sW0[lr * 4 + 1] + zv.z * sW0[lr * 4 + 2] + zv.w * sW0[lr * 4 + 3];
    float p1 = zv.x * sW1[lr * 4] + zv.y * sW1[lr * 4 + 1] + zv.z * sW1[lr * 4 + 2] + zv.w * sW1[lr * 4 + 3];
#pragma unroll
    for (int m = 1; m < 16; m <<= 1) {
        p0 += __shfl_xor(p0, m, 64);
        p1 += __shfl_xor(p1, m, 64);
    }
    if (lr == 0) p[row] = make_float2(p0 + b0, p1 + b1);
}

// ---------------- head: two 8B gathers + softplus per label ----------------

__global__ __launch_bounds__(256) void head_gather(const float2* __restrict__ pu,
                                                   const float2* __restrict__ pm,
                                                   const int* __restrict__ lrow,
                                                   const int* __restrict__ lcol,
                                                   float* __restrict__ out, int B) {
    int i = blockIdx.x * blockDim.x + threadIdx.x;
    int st = gridDim.x * blockDim.x;
    for (int b = i; b < B; b += st) {
        float2 a = pu[lrow[b]];
        float2 d = pm[lcol[b]];
        float m = a.x + d.x;
        float x = a.y + d.y;
        float sp = fmaxf(x, 0.f) + log1pf(expf(-fabsf(x)));
        out[b] = m;
        out[B + b] = sp + 1e-6f;
    }
}

// ---------------- launch ----------------

extern "C" void kernel_launch(void* const* d_in, const int* in_sizes, int n_in,
                              void* d_out, int out_size, void* d_ws, size_t ws_size,
                              hipStream_t stream) {
    const float* x_user  = (const float*)d_in[0];
    const float* x_movie = (const float*)d_in[1];
    const int* src_um = (const int*)d_in[2];
    const int* dst_um = (const int*)d_in[3];
    const int* src_mu = (const int*)d_in[4];
    const int* dst_mu = (const int*)d_in[5];
    const int* lrow = (const int*)d_in[6];
    const int* lcol = (const int*)d_in[7];
    const float* W1_um_l = (const float*)d_in[8];
    const float* b1_um   = (const float*)d_in[9];
    const float* W1_um_r = (const float*)d_in[10];
    const float* W1_mu_l = (const float*)d_in[11];
    const float* b1_mu   = (const float*)d_in[12];
    const float* W1_mu_r = (const float*)d_in[13];
    const float* W2_um_l = (const float*)d_in[14];
    const float* b2_um   = (const float*)d_in[15];
    const float* W2_um_r = (const float*)d_in[16];
    const float* W2_mu_l = (const float*)d_in[17];
    const float* b2_mu   = (const float*)d_in[18];
    const float* W2_mu_r = (const float*)d_in[19];
    const float* W_lin   = (const float*)d_in[20];
    const float* b_lin   = (const float*)d_in[21];
    float* out = (float*)d_out;

    const int E  = in_sizes[2];
    const int B  = in_sizes[6];
    const int NU = in_sizes[0] / 32;   // 100000
    const int NM = in_sizes[1] / 64;   // 20000

    char* wsp = (char*)d_ws;
    size_t o = 0;
    auto alloc = [&](size_t bytes) {
        size_t p = o;
        o += (bytes + 255) & ~(size_t)255;
        return (void*)(wsp + p);
    };
    int* off_um = (int*)alloc((size_t)(NM + 1) * 4);
    int* off_mu = (int*)alloc((size_t)(NU + 1) * 4);
    int* btot   = (int*)alloc((NBALL) * 4);
    int* boff   = (int*)alloc((NBALL + 1) * 4);
    int* csr_um = (int*)alloc((size_t)E * 4);
    int* csr_mu = (int*)alloc((size_t)E * 4);
    float* A_m  = (float*)alloc((size_t)NM * 64 * 4);   // movie mean / z_movie
    float* A_u  = (float*)alloc((size_t)NU * 64 * 4);   // user mean / z_user
    __half* Hh_m = (__half*)alloc((size_t)NM * 64 * 2); // h_movie fp16
    __half* Hh_u = (__half*)alloc((size_t)NU * 64 * 2); // h_user fp16
    __half* xh_u = (__half*)alloc((size_t)NU * 32 * 2); // x_user fp16
    __half* xh_m = (__half*)alloc((size_t)NM * 64 * 2); // x_movie fp16
    float2* pu  = (float2*)alloc((size_t)NU * 8);       // user head projection
    float2* pm  = (float2*)alloc((size_t)NM * 8);       // movie head projection
    (void)ws_size;

    // aliases: consumed before their hosts are first written
    int* tmp   = (int*)A_u;   // [2E] ints = 16 MB <= 25.6 MB; dead after scatter_both
    int* histM = (int*)A_m;   // 353*256*4 = 362 KB; dead after partition2

    const int chunk = (((E + NBLK - 1) / NBLK) + 3) & ~3;  // multiple of 4

    // 0) fp16 copies of input feature tables
    cast_half2<<<512, 256, 0, stream>>>(x_user, xh_u, NU * 32, x_movie, xh_m, NM * 64);

    // 1) CSR build (block-private radix partition)
    hist_part<<<NBLK, 1024, 0, stream>>>(dst_um, dst_mu, histM, E, chunk);
    bucket_totals<<<(NBALL + 3) / 4, 256, 0, stream>>>(histM, btot, NBALL);
    boff_scan<<<1, 256, 0, stream>>>(btot, boff, NBALL, off_um, NM, off_mu, NU, E);
    partition2<<<NBLK, 1024, 0, stream>>>(src_um, dst_um, src_mu, dst_mu, histM, boff,
                                          tmp, E, chunk);
    scatter_both<<<NBALL, 1024, 0, stream>>>(tmp, boff, off_um, csr_um, NM,
                                             off_mu, csr_mu, NU, E);

    // 2) layer 1
    agg_mean_g<32><<<(NM * 4 + 255) / 256, 256, 0, stream>>>(csr_um, off_um, xh_u, A_m, NM);
    dense_mfma<32, 64, true, float, __half><<<(NM + 63) / 64, 256, 0, stream>>>(
        A_m, x_movie, W1_um_l, W1_um_r, b1_um, Hh_m, NM);
    agg_mean_g<64><<<(NU * 8 + 255) / 256, 256, 0, stream>>>(csr_mu, off_mu, xh_m, A_u, NU);
    dense_mfma<64, 32, true, float, __half><<<(NU + 63) / 64, 256, 0, stream>>>(
        A_u, x_user, W1_mu_l, W1_mu_r, b1_mu, Hh_u, NU);

    // 3) layer 2 (dense in-place over the mean buffers; rows staged in LDS first)
    agg_mean_g<64><<<(NM * 8 + 255) / 256, 256, 0, stream>>>(csr_um, off_um, Hh_u, A_m, NM);
    dense_mfma<64, 64, false, __half, float><<<(NM + 63) / 64, 256, 0, stream>>>(
        A_m, Hh_m, W2_um_l, W2_um_r, b2_um, A_m, NM);
    agg_mean_g<64><<<(NU * 8 + 255) / 256, 256, 0, stream>>>(csr_mu, off_mu, Hh_m, A_u, NU);
    dense_mfma<64, 64, false, __half, float><<<(NU + 63) / 64, 256, 0, stream>>>(
        A_u, Hh_u, W2_mu_l, W2_mu_r, b2_mu, A_u, NU);

    // 4) head: project z to 2 dims per node, then gather per label
    proj_kernel<<<(NU + 15) / 16, 256, 0, stream>>>(A_u, W_lin, 0, b_lin, 1, pu, NU);
    proj_kernel<<<(NM + 15) / 16, 256, 0, stream>>>(A_m, W_lin, 64, b_lin, 0, pm, NM);
    head_gather<<<1024, 256, 0, stream>>>(pu, pm, lrow, lcol, out, B);
}

// Round 14
// 245.837 us; speedup vs baseline: 2.0724x; 1.0666x over previous
//
#include <hip/hip_runtime.h>
#include <hip/hip_bf16.h>
#include <hip/hip_fp16.h>
#include <type_traits>

// combined bucket space: um buckets width 256 -> 79; mu buckets width 1024 -> 98
#define NB_UM 79
#define NB_MU 98
#define NBALL 177
#define NBLK 256

using f16x8 = __attribute__((ext_vector_type(8))) _Float16;
using f32x4 = __attribute__((ext_vector_type(4))) float;

// ---------------- cast fp32 -> fp16 tables ----------------

__global__ __launch_bounds__(256) void cast_half2(const float* __restrict__ a,
                                                  __half* __restrict__ ah, int na,
                                                  const float* __restrict__ b,
                                                  __half* __restrict__ bh, int nb) {
    int i = blockIdx.x * blockDim.x + threadIdx.x;
    int st = gridDim.x * blockDim.x;
    for (int k = i; k < na / 2; k += st) {
        float2 v = ((const float2*)a)[k];
        ((__half2*)ah)[k] = __floats2half2_rn(v.x, v.y);
    }
    for (int k = i; k < nb / 2; k += st) {
        float2 v = ((const float2*)b)[k];
        ((__half2*)bh)[k] = __floats2half2_rn(v.x, v.y);
    }
}

// ---------------- pass 1: per-(bucket,block) histogram (int4 loads) ----------------

__global__ __launch_bounds__(1024) void hist_part(const int* __restrict__ dst_um,
                                                  const int* __restrict__ dst_mu,
                                                  int* __restrict__ histM, int E, int chunk) {
    __shared__ int h[NBALL];
    for (int i = threadIdx.x; i < NBALL; i += 1024) h[i] = 0;
    __syncthreads();
    int blk = blockIdx.x;
    int s = blk * chunk, e = min(E, s + chunk);
    if (s < e) {
        int n4 = (e - s) >> 2;
        const int4* du4 = (const int4*)(dst_um + s);
        const int4* dm4 = (const int4*)(dst_mu + s);
        for (int i = threadIdx.x; i < n4; i += 1024) {
            int4 d = du4[i];
            atomicAdd(&h[d.x >> 8], 1);
            atomicAdd(&h[d.y >> 8], 1);
            atomicAdd(&h[d.z >> 8], 1);
            atomicAdd(&h[d.w >> 8], 1);
            int4 m = dm4[i];
            atomicAdd(&h[NB_UM + (m.x >> 10)], 1);
            atomicAdd(&h[NB_UM + (m.y >> 10)], 1);
            atomicAdd(&h[NB_UM + (m.z >> 10)], 1);
            atomicAdd(&h[NB_UM + (m.w >> 10)], 1);
        }
        for (int i = s + (n4 << 2) + threadIdx.x; i < e; i += 1024) {
            atomicAdd(&h[dst_um[i] >> 8], 1);
            atomicAdd(&h[NB_UM + (dst_mu[i] >> 10)], 1);
        }
    }
    __syncthreads();
    for (int i = threadIdx.x; i < NBALL; i += 1024) histM[i * NBLK + blk] = h[i];
}

// ---------------- pass 2: per-bucket wave scan over blocks ----------------

__global__ __launch_bounds__(256) void bucket_totals(int* __restrict__ histM,
                                                     int* __restrict__ btot, int nball) {
    int w = (blockIdx.x * blockDim.x + threadIdx.x) >> 6;
    int lane = threadIdx.x & 63;
    if (w >= nball) return;
    int* row = histM + w * NBLK;
    int v[4];
    int s = 0;
#pragma unroll
    for (int i = 0; i < 4; i++) {
        int c = row[lane * 4 + i];
        v[i] = s;
        s += c;
    }
    int incl = s;
    for (int d = 1; d < 64; d <<= 1) {
        int y = __shfl_up(incl, d, 64);
        if (lane >= d) incl += y;
    }
    int excl = incl - s;
#pragma unroll
    for (int i = 0; i < 4; i++) row[lane * 4 + i] = excl + v[i];
    if (lane == 63) btot[w] = incl;
}

// ---------------- pass 3: scan bucket totals ----------------

__global__ __launch_bounds__(256) void boff_scan(const int* __restrict__ btot,
                                                 int* __restrict__ boff, int nball,
                                                 int* __restrict__ off_um, int NM,
                                                 int* __restrict__ off_mu, int NU, int E) {
    __shared__ int sdata[256];
    int t = threadIdx.x;
    int v[8];
    int sum = 0;
#pragma unroll
    for (int i = 0; i < 8; i++) {
        int idx = t * 8 + i;
        int c = (idx < nball) ? btot[idx] : 0;
        v[i] = sum;
        sum += c;
    }
    sdata[t] = sum;
    __syncthreads();
    for (int s = 1; s < 256; s <<= 1) {
        int y = (t >= s) ? sdata[t - s] : 0;
        __syncthreads();
        sdata[t] += y;
        __syncthreads();
    }
    int base = (t == 0) ? 0 : sdata[t - 1];
#pragma unroll
    for (int i = 0; i < 8; i++) {
        int idx = t * 8 + i;
        if (idx < nball) boff[idx] = base + v[i];
    }
    if (t == 0) {
        boff[nball] = 2 * E;
        off_um[NM] = E;
        off_mu[NU] = E;
    }
}

// ---------------- pass 4: partition (block-private cursors; cur = histM + boff) ----------------

__global__ __launch_bounds__(1024) void partition2(const int* __restrict__ src_um,
                                                   const int* __restrict__ dst_um,
                                                   const int* __restrict__ src_mu,
                                                   const int* __restrict__ dst_mu,
                                                   const int* __restrict__ histM,
                                                   const int* __restrict__ boff,
                                                   int* __restrict__ tmp, int E, int chunk) {
    __shared__ int cur[NBALL];
    int blk = blockIdx.x;
    for (int i = threadIdx.x; i < NBALL; i += 1024)
        cur[i] = histM[i * NBLK + blk] + boff[i];
    __syncthreads();
    int s = blk * chunk, e = min(E, s + chunk);
    if (s >= e) return;
    int n4 = (e - s) >> 2;
    const int4* su4 = (const int4*)(src_um + s);
    const int4* du4 = (const int4*)(dst_um + s);
    const int4* sm4 = (const int4*)(src_mu + s);
    const int4* dm4 = (const int4*)(dst_mu + s);
    for (int i = threadIdx.x; i < n4; i += 1024) {
        int4 sv = su4[i];
        int4 dv = du4[i];
        int p;
        p = atomicAdd(&cur[dv.x >> 8], 1); tmp[p] = sv.x | ((dv.x & 255) << 20);
        p = atomicAdd(&cur[dv.y >> 8], 1); tmp[p] = sv.y | ((dv.y & 255) << 20);
        p = atomicAdd(&cur[dv.z >> 8], 1); tmp[p] = sv.z | ((dv.z & 255) << 20);
        p = atomicAdd(&cur[dv.w >> 8], 1); tmp[p] = sv.w | ((dv.w & 255) << 20);
        int4 sv2 = sm4[i];
        int4 dv2 = dm4[i];
        p = atomicAdd(&cur[NB_UM + (dv2.x >> 10)], 1); tmp[p] = sv2.x | ((dv2.x & 1023) << 20);
        p = atomicAdd(&cur[NB_UM + (dv2.y >> 10)], 1); tmp[p] = sv2.y | ((dv2.y & 1023) << 20);
        p = atomicAdd(&cur[NB_UM + (dv2.z >> 10)], 1); tmp[p] = sv2.z | ((dv2.z & 1023) << 20);
        p = atomicAdd(&cur[NB_UM + (dv2.w >> 10)], 1); tmp[p] = sv2.w | ((dv2.w & 1023) << 20);
    }
    for (int i = s + (n4 << 2) + threadIdx.x; i < e; i += 1024) {
        int d = dst_um[i];
        int p = atomicAdd(&cur[d >> 8], 1);
        tmp[p] = src_um[i] | ((d & 255) << 20);
        int d2 = dst_mu[i];
        int q = atomicAdd(&cur[NB_UM + (d2 >> 10)], 1);
        tmp[q] = src_mu[i] | ((d2 & 1023) << 20);
    }
}

// ---------------- pass 5: per-bucket CSR scatter, both sides in one grid ----------------

__global__ __launch_bounds__(1024) void scatter_both(const int* __restrict__ tmp,
                                                     const int* __restrict__ boff,
                                                     int* __restrict__ off_um,
                                                     int* __restrict__ csr_um, int NM,
                                                     int* __restrict__ off_mu,
                                                     int* __restrict__ csr_mu, int NU, int E) {
    __shared__ int lcnt[1024];
    __shared__ int lcur[1024];
    __shared__ int sdata[1024];
    int b = blockIdx.x;
    int um = (b < NB_UM);
    int W = um ? 256 : 1024;
    int n = um ? NM : NU;
    int sub = um ? 0 : E;
    int* off = um ? off_um : off_mu;
    int* csr = um ? csr_um : csr_mu;
    int rowbase = (um ? b : (b - NB_UM)) * W;
    int t = threadIdx.x;
    int s = boff[b], e = boff[b + 1];
    for (int j = t; j < W; j += 1024) lcnt[j] = 0;
    __syncthreads();
    for (int i = s + t; i < e; i += 1024) atomicAdd(&lcnt[tmp[i] >> 20], 1);
    __syncthreads();
    int myc = (t < W) ? lcnt[t] : 0;
    sdata[t] = myc;
    __syncthreads();
    for (int d = 1; d < 1024; d <<= 1) {
        int y = (t >= d) ? sdata[t - d] : 0;
        __syncthreads();
        sdata[t] += y;
        __syncthreads();
    }
    if (t < W) lcur[t] = s + sdata[t] - myc;
    __syncthreads();
    for (int j = t; j < W; j += 1024)
        if (rowbase + j < n) off[rowbase + j] = lcur[j] - sub;
    __syncthreads();
    for (int i = s + t; i < e; i += 1024) {
        int vv = tmp[i];
        int p = atomicAdd(&lcur[vv >> 20], 1);
        csr[p - sub] = vv & 0xFFFFF;
    }
}

// ---------------- segment mean body (fp16 gather, L-lane group per dst row) ----------------

__device__ __forceinline__ void acc8(float* a, uint4 r) {
    const __half2* h = reinterpret_cast<const __half2*>(&r);
#pragma unroll
    for (int j = 0; j < 4; j++) {
        float2 f = __half22float2(h[j]);
        a[2 * j] += f.x;
        a[2 * j + 1] += f.y;
    }
}

template <int D>
__device__ __forceinline__ void agg_body(const int* __restrict__ csr,
                                         const int* __restrict__ off,
                                         const __half* __restrict__ xh,
                                         float* __restrict__ out, int nrows,
                                         int bid, int nblocks) {
    constexpr int L = D / 8;  // lanes per row
    int gid = (bid * 256 + (int)threadIdx.x) / L;
    int lg = threadIdx.x & (L - 1);
    int ngroups = (nblocks * 256) / L;
    int c8 = lg * 8;
    for (int row = gid; row < nrows; row += ngroups) {
        int s = off[row], e = off[row + 1];
        float a[8] = {0.f, 0.f, 0.f, 0.f, 0.f, 0.f, 0.f, 0.f};
        int k = s;
        for (; k + 4 <= e; k += 4) {
            int i0 = csr[k], i1 = csr[k + 1], i2 = csr[k + 2], i3 = csr[k + 3];
            uint4 r0 = *(const uint4*)&xh[(long)i0 * D + c8];
            uint4 r1 = *(const uint4*)&xh[(long)i1 * D + c8];
            uint4 r2 = *(const uint4*)&xh[(long)i2 * D + c8];
            uint4 r3 = *(const uint4*)&xh[(long)i3 * D + c8];
            acc8(a, r0); acc8(a, r1); acc8(a, r2); acc8(a, r3);
        }
        for (; k < e; ++k) {
            uint4 r0 = *(const uint4*)&xh[(long)csr[k] * D + c8];
            acc8(a, r0);
        }
        float inv = 1.0f / fmaxf((float)(e - s), 1.0f);
        float4 q0 = make_float4(a[0] * inv, a[1] * inv, a[2] * inv, a[3] * inv);
        float4 q1 = make_float4(a[4] * inv, a[5] * inv, a[6] * inv, a[7] * inv);
        *(float4*)&out[(long)row * D + c8] = q0;
        *(float4*)&out[(long)row * D + c8 + 4] = q1;
    }
}

// layer-1 merged aggs: blocks [0,g1): um D=32; [g1,..): mu D=64
__global__ __launch_bounds__(256) void agg_dual_l1(const int* __restrict__ csr_um,
                                                   const int* __restrict__ off_um,
                                                   const __half* __restrict__ xh_u,
                                                   float* __restrict__ A_m, int NM, int g1,
                                                   const int* __restrict__ csr_mu,
                                                   const int* __restrict__ off_mu,
                                                   const __half* __restrict__ xh_m,
                                                   float* __restrict__ A_u, int NU) {
    if ((int)blockIdx.x < g1)
        agg_body<32>(csr_um, off_um, xh_u, A_m, NM, blockIdx.x, g1);
    else
        agg_body<64>(csr_mu, off_mu, xh_m, A_u, NU, blockIdx.x - g1, gridDim.x - g1);
}

// layer-2 merged aggs: both D=64
__global__ __launch_bounds__(256) void agg_dual_l2(const int* __restrict__ csr_um,
                                                   const int* __restrict__ off_um,
                                                   const __half* __restrict__ Hh_u,
                                                   float* __restrict__ A_m, int NM, int g1,
                                                   const int* __restrict__ csr_mu,
                                                   const int* __restrict__ off_mu,
                                                   const __half* __restrict__ Hh_m,
                                                   float* __restrict__ A_u, int NU) {
    if ((int)blockIdx.x < g1)
        agg_body<64>(csr_um, off_um, Hh_u, A_m, NM, blockIdx.x, g1);
    else
        agg_body<64>(csr_mu, off_mu, Hh_m, A_u, NU, blockIdx.x - g1, gridDim.x - g1);
}

// ---------------- dense via MFMA body (R13-proven, R0 = bid*64) ----------------

template <int Dm, int Dd, bool RELU, typename TX, typename TO>
__device__ __forceinline__ void dense_body(char* smemraw,
                                           const float* __restrict__ mean,
                                           const TX* __restrict__ xd,
                                           const float* __restrict__ Wl,
                                           const float* __restrict__ Wr,
                                           const float* __restrict__ bias,
                                           TO* __restrict__ out, int n, int bid) {
    constexpr int K = Dm + Dd;     // 96 or 128
    constexpr int SAP = K + 8;
    _Float16* sA = (_Float16*)smemraw;
    _Float16* sWt = sA + 64 * SAP;
    float* sb = (float*)(sWt + 64 * SAP);
    int t = threadIdx.x;
    int R0 = bid * 64;

    for (int i = t; i < K * 16; i += 256) {
        int k = i >> 4, c = (i & 15) * 4;
        float4 v = (k < Dm) ? *(const float4*)&Wl[k * 64 + c]
                            : *(const float4*)&Wr[(k - Dm) * 64 + c];
        sWt[(c + 0) * SAP + k] = (_Float16)v.x;
        sWt[(c + 1) * SAP + k] = (_Float16)v.y;
        sWt[(c + 2) * SAP + k] = (_Float16)v.z;
        sWt[(c + 3) * SAP + k] = (_Float16)v.w;
    }
    if (t < 64) sb[t] = bias[t];
    constexpr int QR = K / 4;
    for (int i = t; i < 64 * QR; i += 256) {
        int r = i / QR, c = (i % QR) * 4;
        int gr = R0 + r;
        float4 v = make_float4(0.f, 0.f, 0.f, 0.f);
        if (gr < n) {
            if (c < Dm) {
                v = *(const float4*)&mean[(long)gr * Dm + c];
            } else {
                if constexpr (std::is_same<TX, __half>::value) {
                    const __half* p = &xd[(long)gr * Dd + (c - Dm)];
                    v = make_float4(__half2float(p[0]), __half2float(p[1]),
                                    __half2float(p[2]), __half2float(p[3]));
                } else {
                    v = *(const float4*)&xd[(long)gr * Dd + (c - Dm)];
                }
            }
        }
        _Float16* p = &sA[r * SAP + c];
        p[0] = (_Float16)v.x; p[1] = (_Float16)v.y;
        p[2] = (_Float16)v.z; p[3] = (_Float16)v.w;
    }
    __syncthreads();

    int w = t >> 6, lane = t & 63;
    int lr = lane & 15, lg = lane >> 4;
    f32x4 acc[4];
#pragma unroll
    for (int nt = 0; nt < 4; nt++) {
        float bb = sb[16 * nt + lr];
        acc[nt][0] = bb; acc[nt][1] = bb; acc[nt][2] = bb; acc[nt][3] = bb;
    }
    int arow = 16 * w + lr;
#pragma unroll
    for (int kk = 0; kk < K / 32; kk++) {
        int k0 = kk * 32 + 8 * lg;
        f16x8 a = *(const f16x8*)&sA[arow * SAP + k0];
#pragma unroll
        for (int nt = 0; nt < 4; nt++) {
            f16x8 b = *(const f16x8*)&sWt[(16 * nt + lr) * SAP + k0];
            acc[nt] = __builtin_amdgcn_mfma_f32_16x16x32_f16(a, b, acc[nt], 0, 0, 0);
        }
    }
#pragma unroll
    for (int nt = 0; nt < 4; nt++) {
#pragma unroll
        for (int r = 0; r < 4; r++) {
            int gr = R0 + 16 * w + lg * 4 + r;
            if (gr >= n) continue;
            float vv = acc[nt][r];
            if (RELU) vv = fmaxf(vv, 0.f);
            int gc = 16 * nt + lr;
            if constexpr (std::is_same<TO, __half>::value) {
                out[(long)gr * 64 + gc] = __float2half(vv);
            } else {
                out[(long)gr * 64 + gc] = vv;
            }
        }
    }
}

#define DENSE_SMEM_BYTES (64 * 136 * 2 * 2 + 256)

// layer-1 merged denses: [0,g1): um (K=96), rest: mu (K=128)
__global__ __launch_bounds__(256) void dense_dual_l1(const float* __restrict__ A_m,
                                                     const float* __restrict__ x_movie,
                                                     const float* __restrict__ W1l_um,
                                                     const float* __restrict__ W1r_um,
                                                     const float* __restrict__ b1_um,
                                                     __half* __restrict__ Hh_m, int NM, int g1,
                                                     const float* __restrict__ A_u,
                                                     const float* __restrict__ x_user,
                                                     const float* __restrict__ W1l_mu,
                                                     const float* __restrict__ W1r_mu,
                                                     const float* __restrict__ b1_mu,
                                                     __half* __restrict__ Hh_u, int NU) {
    __shared__ __align__(16) char smem[DENSE_SMEM_BYTES];
    if ((int)blockIdx.x < g1)
        dense_body<32, 64, true, float, __half>(smem, A_m, x_movie, W1l_um, W1r_um, b1_um,
                                                Hh_m, NM, blockIdx.x);
    else
        dense_body<64, 32, true, float, __half>(smem, A_u, x_user, W1l_mu, W1r_mu, b1_mu,
                                                Hh_u, NU, blockIdx.x - g1);
}

// layer-2 merged denses: both K=128, fp32 in-place output
__global__ __launch_bounds__(256) void dense_dual_l2(float* __restrict__ A_m,
                                                     const __half* __restrict__ Hh_m,
                                                     const float* __restrict__ W2l_um,
                                                     const float* __restrict__ W2r_um,
                                                     const float* __restrict__ b2_um,
                                                     int NM, int g1,
                                                     float* __restrict__ A_u,
                                                     const __half* __restrict__ Hh_u,
                                                     const float* __restrict__ W2l_mu,
                                                     const float* __restrict__ W2r_mu,
                                                     const float* __restrict__ b2_mu,
                                                     int NU) {
    __shared__ __align__(16) char smem[DENSE_SMEM_BYTES];
    if ((int)blockIdx.x < g1)
        dense_body<64, 64, false, __half, float>(smem, A_m, Hh_m, W2l_um, W2r_um, b2_um,
                                                 A_m, NM, blockIdx.x);
    else
        dense_body<64, 64, false, __half, float>(smem, A_u, Hh_u, W2l_mu, W2r_mu, b2_mu,
                                                 A_u, NU, blockIdx.x - g1);
}

// ---------------- merged head projections ----------------
// blocks [0,gu): user rows (woff 0, +blin); rest: movie rows (woff 64)

__global__ __launch_bounds__(256) void proj_dual(const float* __restrict__ zu,
                                                 const float* __restrict__ zm,
                                                 const float* __restrict__ Wlin,
                                                 const float* __restrict__ blin,
                                                 float2* __restrict__ pu,
                                                 float2* __restrict__ pm,
                                                 int NU, int NM, int gu) {
    int isu = ((int)blockIdx.x < gu);
    const float* z = isu ? zu : zm;
    float2* p = isu ? pu : pm;
    int n = isu ? NU : NM;
    int woff = isu ? 0 : 64;
    int bid = isu ? blockIdx.x : blockIdx.x - gu;
    __shared__ float sW0[64], sW1[64];
    int t = threadIdx.x;
    if (t < 64) {
        sW0[t] = Wlin[(woff + t) * 2 + 0];
        sW1[t] = Wlin[(woff + t) * 2 + 1];
    }
    __syncthreads();
    float b0 = isu ? blin[0] : 0.f;
    float b1 = isu ? blin[1] : 0.f;
    int lane = t & 63;
    int w = t >> 6;
    int lr = lane & 15, q = lane >> 4;
    int row = bid * 16 + w * 4 + q;
    if (row >= n) return;
    float4 zv = *(const float4*)&z[(long)row * 64 + lr * 4];
    float p0 = zv.x * sW0[lr * 4] + zv.y * sW0[lr * 4 + 1] + zv.z * sW0[lr * 4 + 2] + zv.w * sW0[lr * 4 + 3];
    float p1 = zv.x * sW1[lr * 4] + zv.y * sW1[lr * 4 + 1] + zv.z * sW1[lr * 4 + 2] + zv.w * sW1[lr * 4 + 3];
#pragma unroll
    for (int m = 1; m < 16; m <<= 1) {
        p0 += __shfl_xor(p0, m, 64);
        p1 += __shfl_xor(p1, m, 64);
    }
    if (lr == 0) p[row] = make_float2(p0 + b0, p1 + b1);
}

// ---------------- head: two 8B gathers + softplus per label ----------------

__global__ __launch_bounds__(256) void head_gather(const float2* __restrict__ pu,
                                                   const float2* __restrict__ pm,
                                                   const int* __restrict__ lrow,
                                                   const int* __restrict__ lcol,
                                                   float* __restrict__ out, int B) {
    int i = blockIdx.x * blockDim.x + threadIdx.x;
    int st = gridDim.x * blockDim.x;
    for (int b = i; b < B; b += st) {
        float2 a = pu[lrow[b]];
        float2 d = pm[lcol[b]];
        float m = a.x + d.x;
        float x = a.y + d.y;
        float sp = fmaxf(x, 0.f) + log1pf(expf(-fabsf(x)));
        out[b] = m;
        out[B + b] = sp + 1e-6f;
    }
}

// ---------------- launch ----------------

extern "C" void kernel_launch(void* const* d_in, const int* in_sizes, int n_in,
                              void* d_out, int out_size, void* d_ws, size_t ws_size,
                              hipStream_t stream) {
    const float* x_user  = (const float*)d_in[0];
    const float* x_movie = (const float*)d_in[1];
    const int* src_um = (const int*)d_in[2];
    const int* dst_um = (const int*)d_in[3];
    const int* src_mu = (const int*)d_in[4];
    const int* dst_mu = (const int*)d_in[5];
    const int* lrow = (const int*)d_in[6];
    const int* lcol = (const int*)d_in[7];
    const float* W1_um_l = (const float*)d_in[8];
    const float* b1_um   = (const float*)d_in[9];
    const float* W1_um_r = (const float*)d_in[10];
    const float* W1_mu_l = (const float*)d_in[11];
    const float* b1_mu   = (const float*)d_in[12];
    const float* W1_mu_r = (const float*)d_in[13];
    const float* W2_um_l = (const float*)d_in[14];
    const float* b2_um   = (const float*)d_in[15];
    const float* W2_um_r = (const float*)d_in[16];
    const float* W2_mu_l = (const float*)d_in[17];
    const float* b2_mu   = (const float*)d_in[18];
    const float* W2_mu_r = (const float*)d_in[19];
    const float* W_lin   = (const float*)d_in[20];
    const float* b_lin   = (const float*)d_in[21];
    float* out = (float*)d_out;

    const int E  = in_sizes[2];
    const int B  = in_sizes[6];
    const int NU = in_sizes[0] / 32;   // 100000
    const int NM = in_sizes[1] / 64;   // 20000

    char* wsp = (char*)d_ws;
    size_t o = 0;
    auto alloc = [&](size_t bytes) {
        size_t p = o;
        o += (bytes + 255) & ~(size_t)255;
        return (void*)(wsp + p);
    };
    int* off_um = (int*)alloc((size_t)(NM + 1) * 4);
    int* off_mu = (int*)alloc((size_t)(NU + 1) * 4);
    int* btot   = (int*)alloc((NBALL) * 4);
    int* boff   = (int*)alloc((NBALL + 1) * 4);
    int* csr_um = (int*)alloc((size_t)E * 4);
    int* csr_mu = (int*)alloc((size_t)E * 4);
    float* A_m  = (float*)alloc((size_t)NM * 64 * 4);   // movie mean / z_movie
    float* A_u  = (float*)alloc((size_t)NU * 64 * 4);   // user mean / z_user
    __half* Hh_m = (__half*)alloc((size_t)NM * 64 * 2); // h_movie fp16
    __half* Hh_u = (__half*)alloc((size_t)NU * 64 * 2); // h_user fp16
    __half* xh_u = (__half*)alloc((size_t)NU * 32 * 2); // x_user fp16
    __half* xh_m = (__half*)alloc((size_t)NM * 64 * 2); // x_movie fp16
    float2* pu  = (float2*)alloc((size_t)NU * 8);       // user head projection
    float2* pm  = (float2*)alloc((size_t)NM * 8);       // movie head projection
    (void)ws_size;

    // aliases: consumed before their hosts are first written
    int* tmp   = (int*)A_u;   // [2E] ints = 16 MB <= 25.6 MB; dead after scatter_both
    int* histM = (int*)A_m;   // 177*256*4 = 181 KB; dead after partition2

    const int chunk = (((E + NBLK - 1) / NBLK) + 3) & ~3;  // multiple of 4

    // 0) fp16 copies of input feature tables
    cast_half2<<<512, 256, 0, stream>>>(x_user, xh_u, NU * 32, x_movie, xh_m, NM * 64);

    // 1) CSR build (block-private radix partition)
    hist_part<<<NBLK, 1024, 0, stream>>>(dst_um, dst_mu, histM, E, chunk);
    bucket_totals<<<(NBALL + 3) / 4, 256, 0, stream>>>(histM, btot, NBALL);
    boff_scan<<<1, 256, 0, stream>>>(btot, boff, NBALL, off_um, NM, off_mu, NU, E);
    partition2<<<NBLK, 1024, 0, stream>>>(src_um, dst_um, src_mu, dst_mu, histM, boff,
                                          tmp, E, chunk);
    scatter_both<<<NBALL, 1024, 0, stream>>>(tmp, boff, off_um, csr_um, NM,
                                             off_mu, csr_mu, NU, E);

    // 2) layer 1: merged aggs, then merged denses
    {
        int g1 = (NM * 4 + 255) / 256;   // um D=32 groups
        int g2 = (NU * 8 + 255) / 256;   // mu D=64 groups
        agg_dual_l1<<<g1 + g2, 256, 0, stream>>>(csr_um, off_um, xh_u, A_m, NM, g1,
                                                 csr_mu, off_mu, xh_m, A_u, NU);
        int d1 = (NM + 63) / 64, d2 = (NU + 63) / 64;
        dense_dual_l1<<<d1 + d2, 256, 0, stream>>>(A_m, x_movie, W1_um_l, W1_um_r, b1_um,
                                                   Hh_m, NM, d1,
                                                   A_u, x_user, W1_mu_l, W1_mu_r, b1_mu,
                                                   Hh_u, NU);
    }

    // 3) layer 2: merged aggs, then merged denses (in-place over mean buffers)
    {
        int g1 = (NM * 8 + 255) / 256;
        int g2 = (NU * 8 + 255) / 256;
        agg_dual_l2<<<g1 + g2, 256, 0, stream>>>(csr_um, off_um, Hh_u, A_m, NM, g1,
                                                 csr_mu, off_mu, Hh_m, A_u, NU);
        int d1 = (NM + 63) / 64, d2 = (NU + 63) / 64;
        dense_dual_l2<<<d1 + d2, 256, 0, stream>>>(A_m, Hh_m, W2_um_l, W2_um_r, b2_um, NM, d1,
                                                   A_u, Hh_u, W2_mu_l, W2_mu_r, b2_mu, NU);
    }

    // 4) head: merged projections, then gather
    {
        int gu = (NU + 15) / 16, gm = (NM + 15) / 16;
        proj_dual<<<gu + gm, 256, 0, stream>>>(A_u, A_m, W_lin, b_lin, pu, pm, NU, NM, gu);
    }
    head_gather<<<1024, 256, 0, stream>>>(pu, pm, lrow, lcol, out, B);
}